// Round 1
// baseline (2418.678 us; speedup 1.0000x reference)
//
#include <hip/hip_runtime.h>
#include <math.h>

#define HIDDEN 256
#define HEADS 4
#define HEAD_DIM 64
#define LAYERS 3
#define NUM_GRAPHS 64
#define NEG_SLOPE 0.2f

// ---------- helpers ----------
static __device__ __forceinline__ float elu_f(float x) {
    return x > 0.f ? x : expm1f(x);
}

static __device__ __forceinline__ float waveReduceSum(float v) {
#pragma unroll
    for (int off = 32; off > 0; off >>= 1) v += __shfl_xor(v, off, 64);
    return v;
}

// monotone float -> uint mapping for atomicMax on floats
static __device__ __forceinline__ unsigned mapf(float x) {
    unsigned u = __float_as_uint(x);
    return (u & 0x80000000u) ? ~u : (u | 0x80000000u);
}
static __device__ __forceinline__ float unmapf(unsigned u) {
    return (u & 0x80000000u) ? __uint_as_float(u & 0x7FFFFFFFu) : __uint_as_float(~u);
}

// ---------- CSR build ----------
__global__ void hist_kernel(const int* __restrict__ dst, int* __restrict__ deg, int E) {
    int e = blockIdx.x * blockDim.x + threadIdx.x;
    if (e < E) atomicAdd(&deg[dst[e]], 1);
}

__global__ void scan_kernel(const int* __restrict__ deg, int* __restrict__ rowptr, int N, int E) {
    __shared__ int part[256];
    __shared__ int offs[256];
    int t = threadIdx.x;
    int chunk = (N + 255) / 256;
    int b0 = t * chunk;
    int b1 = min(b0 + chunk, N);
    int s = 0;
    for (int i = b0; i < b1; ++i) s += deg[i];
    part[t] = s;
    __syncthreads();
    if (t == 0) {
        int run = 0;
        for (int i = 0; i < 256; ++i) { offs[i] = run; run += part[i]; }
    }
    __syncthreads();
    int run = offs[t];
    for (int i = b0; i < b1; ++i) { rowptr[i] = run; run += deg[i]; }
    if (t == 0) rowptr[N] = E;
}

__global__ void copy_int(const int* __restrict__ a, int* __restrict__ b, int n) {
    int i = blockIdx.x * blockDim.x + threadIdx.x;
    if (i < n) b[i] = a[i];
}

__global__ void scatter_kernel(const int* __restrict__ dst, int* __restrict__ nxt,
                               int* __restrict__ eid, int E) {
    int e = blockIdx.x * blockDim.x + threadIdx.x;
    if (e < E) {
        int slot = atomicAdd(&nxt[dst[e]], 1);
        eid[slot] = e;
    }
}

// ---------- tiny precompute: w_ea[l][h][k] = sum_d We[l,k,h*64+d] * a_e[l,h,d] ----------
__global__ void wea_kernel(const float* __restrict__ We, const float* __restrict__ a_e,
                           float* __restrict__ w_ea) {
    int t = threadIdx.x;
    if (t < LAYERS * HEADS * 3) {
        int l = t / 12, r = t % 12, h = r / 3, k = r % 3;
        float s = 0.f;
        for (int d = 0; d < HEAD_DIM; ++d)
            s += We[l * 3 * HIDDEN + k * HIDDEN + h * HEAD_DIM + d] *
                 a_e[l * HIDDEN + h * HEAD_DIM + d];
        w_ea[t] = s;
    }
}

// ---------- input projection + LayerNorm + ELU ----------
__global__ __launch_bounds__(256) void inproj_ln(const float* __restrict__ x,
                                                 const float* __restrict__ W,
                                                 const float* __restrict__ b,
                                                 const float* __restrict__ g,
                                                 const float* __restrict__ beta,
                                                 float* __restrict__ h) {
    int n = blockIdx.x;
    int c = threadIdx.x;
    float acc = b[c];
#pragma unroll
    for (int k = 0; k < 8; ++k) acc += x[n * 8 + k] * W[k * HIDDEN + c];
    __shared__ float red[8];
    float s = waveReduceSum(acc);
    float s2 = waveReduceSum(acc * acc);
    int w = c >> 6;
    if ((c & 63) == 0) { red[w] = s; red[4 + w] = s2; }
    __syncthreads();
    float mu = (red[0] + red[1] + red[2] + red[3]) * (1.f / 256.f);
    float ms = (red[4] + red[5] + red[6] + red[7]) * (1.f / 256.f);
    float inv = rsqrtf(ms - mu * mu + 1e-5f);
    float y = (acc - mu) * inv * g[c] + beta[c];
    h[(size_t)n * HIDDEN + c] = elu_f(y);
}

// ---------- LayerNorm + ELU on precomputed input ----------
__global__ __launch_bounds__(256) void ln_elu(const float* __restrict__ t,
                                              const float* __restrict__ g,
                                              const float* __restrict__ beta,
                                              float* __restrict__ out) {
    int n = blockIdx.x;
    int c = threadIdx.x;
    float acc = t[(size_t)n * HIDDEN + c];
    __shared__ float red[8];
    float s = waveReduceSum(acc);
    float s2 = waveReduceSum(acc * acc);
    int w = c >> 6;
    if ((c & 63) == 0) { red[w] = s; red[4 + w] = s2; }
    __syncthreads();
    float mu = (red[0] + red[1] + red[2] + red[3]) * (1.f / 256.f);
    float ms = (red[4] + red[5] + red[6] + red[7]) * (1.f / 256.f);
    float inv = rsqrtf(ms - mu * mu + 1e-5f);
    float y = (acc - mu) * inv * g[c] + beta[c];
    out[(size_t)n * HIDDEN + c] = elu_f(y);
}

// ---------- fp32 GEMM: C[M,N] = A[M,K] @ B[K,N] + bias[N] ----------
#define BM 128
#define BN 128
#define BK 16
__global__ __launch_bounds__(256) void gemm_bias(const float* __restrict__ A,
                                                 const float* __restrict__ B,
                                                 const float* __restrict__ bias,
                                                 float* __restrict__ C,
                                                 int M, int N, int K) {
    __shared__ float As[BK][BM];
    __shared__ float Bs[BK][BN];
    int m0 = blockIdx.x * BM;
    int n0 = blockIdx.y * BN;
    int tid = threadIdx.x;
    int tx = tid & 15, ty = tid >> 4;
    float acc[8][8] = {};
    for (int k0 = 0; k0 < K; k0 += BK) {
#pragma unroll
        for (int i = 0; i < 8; ++i) {
            int idx = tid + i * 256;   // 0..2047 over 128x16
            int m = idx >> 4;
            int k = idx & 15;
            float v = 0.f;
            if (m0 + m < M) v = A[(size_t)(m0 + m) * K + k0 + k];
            As[k][m] = v;
        }
#pragma unroll
        for (int i = 0; i < 8; ++i) {
            int idx = tid + i * 256;   // 0..2047 over 16x128
            int k = idx >> 7;
            int n = idx & 127;
            Bs[k][n] = B[(size_t)(k0 + k) * N + n0 + n];
        }
        __syncthreads();
#pragma unroll
        for (int k = 0; k < BK; ++k) {
            float a[8], b[8];
#pragma unroll
            for (int i = 0; i < 8; ++i) a[i] = As[k][ty * 8 + i];
#pragma unroll
            for (int j = 0; j < 8; ++j) b[j] = Bs[k][tx * 8 + j];
#pragma unroll
            for (int i = 0; i < 8; ++i)
#pragma unroll
                for (int j = 0; j < 8; ++j) acc[i][j] += a[i] * b[j];
        }
        __syncthreads();
    }
#pragma unroll
    for (int i = 0; i < 8; ++i) {
        int m = m0 + ty * 8 + i;
        if (m < M) {
#pragma unroll
            for (int j = 0; j < 8; ++j) {
                int n = n0 + tx * 8 + j;
                C[(size_t)m * N + n] = acc[i][j] + bias[n];
            }
        }
    }
}

// ---------- per-node attention scores: s_src[n,h] = hp[n,h,:].a_s[h,:] ----------
__global__ __launch_bounds__(256) void scores_kernel(const float* __restrict__ hp,
                                                     const float* __restrict__ a_s,
                                                     const float* __restrict__ a_d,
                                                     float* __restrict__ s_src,
                                                     float* __restrict__ s_dst) {
    int n = blockIdx.x;
    int c = threadIdx.x;
    int w = c >> 6, lane = c & 63;
    float v = hp[(size_t)n * HIDDEN + c];
    float ps = waveReduceSum(v * a_s[c]);
    float pd = waveReduceSum(v * a_d[c]);
    if (lane == 0) {
        s_src[n * 4 + w] = ps;
        s_dst[n * 4 + w] = pd;
    }
}

// ---------- per-edge logits + segment max ----------
__global__ __launch_bounds__(256) void edge_logits(const int* __restrict__ src,
                                                   const int* __restrict__ dst,
                                                   const float* __restrict__ ea,
                                                   const float* __restrict__ s_src,
                                                   const float* __restrict__ s_dst,
                                                   const float* __restrict__ w_ea,
                                                   float* __restrict__ logit,
                                                   unsigned* __restrict__ mbuf, int E) {
    int e = blockIdx.x * blockDim.x + threadIdx.x;
    if (e >= E) return;
    int s = src[e], d = dst[e];
    float4 ss = *(const float4*)(s_src + (size_t)s * 4);
    float4 sd = *(const float4*)(s_dst + (size_t)d * 4);
    float e0 = ea[(size_t)e * 3], e1 = ea[(size_t)e * 3 + 1], e2 = ea[(size_t)e * 3 + 2];
    float ssv[4] = {ss.x, ss.y, ss.z, ss.w};
    float sdv[4] = {sd.x, sd.y, sd.z, sd.w};
#pragma unroll
    for (int h = 0; h < 4; ++h) {
        float esc = e0 * w_ea[h * 3] + e1 * w_ea[h * 3 + 1] + e2 * w_ea[h * 3 + 2];
        float lg = ssv[h] + sdv[h] + esc;
        lg = lg > 0.f ? lg : NEG_SLOPE * lg;
        logit[(size_t)e * 4 + h] = lg;
        atomicMax(&mbuf[d * 4 + h], mapf(lg));
    }
}

// ---------- per-node aggregation (CSR), normalize, residual, ELU ----------
__global__ __launch_bounds__(256) void aggregate(const int* __restrict__ rowptr,
                                                 const int* __restrict__ eid,
                                                 const int* __restrict__ src,
                                                 const float* __restrict__ logit,
                                                 const unsigned* __restrict__ mbuf,
                                                 const float* __restrict__ hp,
                                                 const float* __restrict__ h_in,
                                                 float* __restrict__ h_out) {
    int n = blockIdx.x;
    int c = threadIdx.x;
    int h = c >> 6;
    float mh = unmapf(mbuf[n * 4 + h]);
    int beg = rowptr[n], end = rowptr[n + 1];
    float acc = 0.f, dsum = 0.f;
    for (int i = beg; i < end; ++i) {
        int e = eid[i];
        int s = src[e];
        float ex = expf(logit[(size_t)e * 4 + h] - mh);
        dsum += ex;
        acc += hp[(size_t)s * HIDDEN + c] * ex;
    }
    float out = acc / fmaxf(dsum, 1e-16f);
    float r = out + h_in[(size_t)n * HIDDEN + c];
    h_out[(size_t)n * HIDDEN + c] = elu_f(r);
}

// ---------- per-graph mean pool (batch is sorted) ----------
__global__ __launch_bounds__(256) void pool_kernel(const float* __restrict__ node_emb,
                                                   const int* __restrict__ batch,
                                                   float* __restrict__ gout, int N) {
    int g = blockIdx.x;
    int c = threadIdx.x;
    int lo = 0, hi = N;
    while (lo < hi) { int mid = (lo + hi) >> 1; if (batch[mid] < g) lo = mid + 1; else hi = mid; }
    int start = lo;
    lo = start; hi = N;
    while (lo < hi) { int mid = (lo + hi) >> 1; if (batch[mid] < g + 1) lo = mid + 1; else hi = mid; }
    int end = lo;
    float s = 0.f;
    for (int n = start; n < end; ++n) s += node_emb[(size_t)n * HIDDEN + c];
    float cnt = (float)(end - start);
    gout[g * HIDDEN + c] = s / fmaxf(cnt, 1.f);
}

extern "C" void kernel_launch(void* const* d_in, const int* in_sizes, int n_in,
                              void* d_out, int out_size, void* d_ws, size_t ws_size,
                              hipStream_t stream) {
    const float* x       = (const float*)d_in[0];
    const int*   ei      = (const int*)d_in[1];
    const float* ea      = (const float*)d_in[2];
    const int*   batch   = (const int*)d_in[3];
    const float* W_in    = (const float*)d_in[4];
    const float* b_in    = (const float*)d_in[5];
    const float* ln_in_g = (const float*)d_in[6];
    const float* ln_in_b = (const float*)d_in[7];
    const float* W_gat   = (const float*)d_in[8];
    const float* b_gat   = (const float*)d_in[9];
    const float* W_e     = (const float*)d_in[10];
    const float* a_src   = (const float*)d_in[11];
    const float* a_dst   = (const float*)d_in[12];
    const float* a_edge  = (const float*)d_in[13];
    const float* W_out   = (const float*)d_in[14];
    const float* b_out   = (const float*)d_in[15];
    const float* ln_out_g= (const float*)d_in[16];
    const float* ln_out_b= (const float*)d_in[17];

    int N = in_sizes[0] / 8;
    int E = in_sizes[1] / 2;
    const int* srcA = ei;
    const int* dstA = ei + E;

    char* w = (char*)d_ws;
    size_t off = 0;
    auto alloc = [&](size_t bytes) {
        void* p = w + off;
        off += (bytes + 255) & ~(size_t)255;
        return p;
    };
    float*    hA     = (float*)alloc((size_t)N * HIDDEN * 4);
    float*    hB     = (float*)alloc((size_t)N * HIDDEN * 4);
    float*    hp     = (float*)alloc((size_t)N * HIDDEN * 4);
    float*    sSrc   = (float*)alloc((size_t)N * 4 * 4);
    float*    sDst   = (float*)alloc((size_t)N * 4 * 4);
    float*    logit  = (float*)alloc((size_t)E * 4 * 4);
    unsigned* mbuf   = (unsigned*)alloc((size_t)N * 4 * 4);
    int*      deg    = (int*)alloc((size_t)N * 4);
    int*      rowptr = (int*)alloc((size_t)(N + 1) * 4);
    int*      nxt    = (int*)alloc((size_t)N * 4);
    int*      eid    = (int*)alloc((size_t)E * 4);
    float*    wea    = (float*)alloc(64 * 4);

    // --- CSR by dst (built every call; inputs restored each call) ---
    hipMemsetAsync(deg, 0, (size_t)N * 4, stream);
    hist_kernel<<<(E + 255) / 256, 256, 0, stream>>>(dstA, deg, E);
    scan_kernel<<<1, 256, 0, stream>>>(deg, rowptr, N, E);
    copy_int<<<(N + 255) / 256, 256, 0, stream>>>(rowptr, nxt, N);
    scatter_kernel<<<(E + 255) / 256, 256, 0, stream>>>(dstA, nxt, eid, E);
    wea_kernel<<<1, 64, 0, stream>>>(W_e, a_edge, wea);

    // --- input projection + LN + ELU ---
    inproj_ln<<<N, 256, 0, stream>>>(x, W_in, b_in, ln_in_g, ln_in_b, hA);

    float* hcur = hA;
    float* hnext = hB;
    for (int l = 0; l < LAYERS; ++l) {
        dim3 gg((N + BM - 1) / BM, HIDDEN / BN);
        gemm_bias<<<gg, 256, 0, stream>>>(hcur, W_gat + (size_t)l * HIDDEN * HIDDEN,
                                          b_gat + l * HIDDEN, hp, N, HIDDEN, HIDDEN);
        scores_kernel<<<N, 256, 0, stream>>>(hp, a_src + l * HIDDEN, a_dst + l * HIDDEN,
                                             sSrc, sDst);
        hipMemsetAsync(mbuf, 0, (size_t)N * 16, stream);
        edge_logits<<<(E + 255) / 256, 256, 0, stream>>>(srcA, dstA, ea, sSrc, sDst,
                                                         wea + l * 12, logit, mbuf, E);
        aggregate<<<N, 256, 0, stream>>>(rowptr, eid, srcA, logit, mbuf, hp, hcur, hnext);
        float* t = hcur; hcur = hnext; hnext = t;
    }

    // --- output projection + LN + ELU -> node_emb; then pool -> graph_emb ---
    gemm_bias<<<dim3((N + BM - 1) / BM, HIDDEN / BN), 256, 0, stream>>>(
        hcur, W_out, b_out, hp, N, HIDDEN, HIDDEN);
    float* gout = (float*)d_out;
    float* nemb = gout + (size_t)NUM_GRAPHS * HIDDEN;
    ln_elu<<<N, 256, 0, stream>>>(hp, ln_out_g, ln_out_b, nemb);
    pool_kernel<<<NUM_GRAPHS, 256, 0, stream>>>(nemb, batch, gout, N);
}

// Round 2
// 1615.710 us; speedup vs baseline: 1.4970x; 1.4970x over previous
//
#include <hip/hip_runtime.h>
#include <math.h>

#define HIDDEN 256
#define HEADS 4
#define HEAD_DIM 64
#define LAYERS 3
#define NUM_GRAPHS 64
#define NEG_SLOPE 0.2f

typedef short short8 __attribute__((ext_vector_type(8)));
typedef float floatx4 __attribute__((ext_vector_type(4)));

// ---------- helpers ----------
static __device__ __forceinline__ float elu_f(float x) {
    return x > 0.f ? x : expm1f(x);
}

static __device__ __forceinline__ float waveReduceSum(float v) {
#pragma unroll
    for (int off = 32; off > 0; off >>= 1) v += __shfl_xor(v, off, 64);
    return v;
}

// fp32 <-> bf16 (RNE)
static __device__ __forceinline__ ushort f2bf(float f) {
    unsigned u = __float_as_uint(f);
    unsigned r = (u + 0x7FFFu + ((u >> 16) & 1u)) >> 16;
    return (ushort)r;
}
static __device__ __forceinline__ float bf2f(ushort h) {
    return __uint_as_float(((unsigned)h) << 16);
}

// monotone float -> uint mapping for atomicMax on floats
static __device__ __forceinline__ unsigned mapf(float x) {
    unsigned u = __float_as_uint(x);
    return (u & 0x80000000u) ? ~u : (u | 0x80000000u);
}
static __device__ __forceinline__ float unmapf(unsigned u) {
    return (u & 0x80000000u) ? __uint_as_float(u & 0x7FFFFFFFu) : __uint_as_float(~u);
}

// ---------- CSR build ----------
__global__ void hist_kernel(const int* __restrict__ dst, int* __restrict__ deg, int E) {
    int e = blockIdx.x * blockDim.x + threadIdx.x;
    if (e < E) atomicAdd(&deg[dst[e]], 1);
}

__global__ void scan_kernel(const int* __restrict__ deg, int* __restrict__ rowptr, int N, int E) {
    __shared__ int part[256];
    __shared__ int offs[256];
    int t = threadIdx.x;
    int chunk = (N + 255) / 256;
    int b0 = t * chunk;
    int b1 = min(b0 + chunk, N);
    int s = 0;
    for (int i = b0; i < b1; ++i) s += deg[i];
    part[t] = s;
    __syncthreads();
    if (t == 0) {
        int run = 0;
        for (int i = 0; i < 256; ++i) { offs[i] = run; run += part[i]; }
    }
    __syncthreads();
    int run = offs[t];
    for (int i = b0; i < b1; ++i) { rowptr[i] = run; run += deg[i]; }
    if (t == 0) rowptr[N] = E;
}

__global__ void copy_int(const int* __restrict__ a, int* __restrict__ b, int n) {
    int i = blockIdx.x * blockDim.x + threadIdx.x;
    if (i < n) b[i] = a[i];
}

__global__ void scatter_kernel(const int* __restrict__ dst, int* __restrict__ nxt,
                               int* __restrict__ eid, int E) {
    int e = blockIdx.x * blockDim.x + threadIdx.x;
    if (e < E) {
        int slot = atomicAdd(&nxt[dst[e]], 1);
        eid[slot] = e;
    }
}

// ---------- tiny precompute: w_ea[l][h][k] = sum_d We[l,k,h*64+d] * a_e[l,h,d] ----------
__global__ void wea_kernel(const float* __restrict__ We, const float* __restrict__ a_e,
                           float* __restrict__ w_ea) {
    int t = threadIdx.x;
    if (t < LAYERS * HEADS * 3) {
        int l = t / 12, r = t % 12, h = r / 3, k = r % 3;
        float s = 0.f;
        for (int d = 0; d < HEAD_DIM; ++d)
            s += We[l * 3 * HIDDEN + k * HIDDEN + h * HEAD_DIM + d] *
                 a_e[l * HIDDEN + h * HEAD_DIM + d];
        w_ea[t] = s;
    }
}

// ---------- weight convert+transpose: Wt[l][n][k] = bf16(W_l[k][n]) ----------
__global__ void conv_w(const float* __restrict__ Wg, const float* __restrict__ Wo,
                       ushort* __restrict__ Wt) {
    int l = blockIdx.x;      // 0..3  (0..2 = GAT layers, 3 = W_out)
    int n = blockIdx.y;      // 0..255
    int k = threadIdx.x;     // 0..255
    const float* W = (l < 3) ? (Wg + (size_t)l * HIDDEN * HIDDEN) : Wo;
    Wt[(size_t)l * HIDDEN * HIDDEN + (size_t)n * HIDDEN + k] =
        f2bf(W[(size_t)k * HIDDEN + n]);
}

// ---------- input projection + LayerNorm + ELU (fp32 + bf16 outputs) ----------
__global__ __launch_bounds__(256) void inproj_ln(const float* __restrict__ x,
                                                 const float* __restrict__ W,
                                                 const float* __restrict__ b,
                                                 const float* __restrict__ g,
                                                 const float* __restrict__ beta,
                                                 float* __restrict__ h,
                                                 ushort* __restrict__ hb) {
    int n = blockIdx.x;
    int c = threadIdx.x;
    float acc = b[c];
#pragma unroll
    for (int k = 0; k < 8; ++k) acc += x[n * 8 + k] * W[k * HIDDEN + c];
    __shared__ float red[8];
    float s = waveReduceSum(acc);
    float s2 = waveReduceSum(acc * acc);
    int w = c >> 6;
    if ((c & 63) == 0) { red[w] = s; red[4 + w] = s2; }
    __syncthreads();
    float mu = (red[0] + red[1] + red[2] + red[3]) * (1.f / 256.f);
    float ms = (red[4] + red[5] + red[6] + red[7]) * (1.f / 256.f);
    float inv = rsqrtf(ms - mu * mu + 1e-5f);
    float y = elu_f((acc - mu) * inv * g[c] + beta[c]);
    h[(size_t)n * HIDDEN + c] = y;
    hb[(size_t)n * HIDDEN + c] = f2bf(y);
}

// ---------- LayerNorm + ELU (final, fp32 input) ----------
__global__ __launch_bounds__(256) void ln_elu(const float* __restrict__ t,
                                              const float* __restrict__ g,
                                              const float* __restrict__ beta,
                                              float* __restrict__ out) {
    int n = blockIdx.x;
    int c = threadIdx.x;
    float acc = t[(size_t)n * HIDDEN + c];
    __shared__ float red[8];
    float s = waveReduceSum(acc);
    float s2 = waveReduceSum(acc * acc);
    int w = c >> 6;
    if ((c & 63) == 0) { red[w] = s; red[4 + w] = s2; }
    __syncthreads();
    float mu = (red[0] + red[1] + red[2] + red[3]) * (1.f / 256.f);
    float ms = (red[4] + red[5] + red[6] + red[7]) * (1.f / 256.f);
    float inv = rsqrtf(ms - mu * mu + 1e-5f);
    float y = (acc - mu) * inv * g[c] + beta[c];
    out[(size_t)n * HIDDEN + c] = elu_f(y);
}

// ---------- bf16 MFMA GEMM: C[M,256] = A[M,256] @ Bt[n][k]^T + bias ----------
// A: bf16 row-major [Mpad][256]; Bt: bf16 [256 n][256 k] (pre-transposed weight).
// 128x128 block tile, 4 waves in 2x2, each wave 64x64 via 4x4 mfma_16x16x32.
// A-frag: lane holds A[m=lane&15][k=(lane>>4)*8+j]; B-frag mirrors with n=lane&15.
// C/D: col=lane&15, row=(lane>>4)*4+reg  [guide §3, m89/m91 verified].
#define ASTR 40   // padded LDS row stride (ushorts) to spread banks
__global__ __launch_bounds__(256) void gemm_mfma(const ushort* __restrict__ A,
                                                 const ushort* __restrict__ Bt,
                                                 const float* __restrict__ bias,
                                                 float* __restrict__ C32,
                                                 ushort* __restrict__ C16,
                                                 int Mpad) {
    const int K = 256;
    __shared__ ushort As[128 * ASTR];
    __shared__ ushort Bs[128 * ASTR];
    int m0 = blockIdx.x * 128;
    int n0 = blockIdx.y * 128;
    int t = threadIdx.x;
    int wave = t >> 6, lane = t & 63;
    int wr = wave >> 1, wc = wave & 1;
    int lrow = lane & 15;
    int quad = lane >> 4;
    floatx4 acc[4][4] = {};
    int r = t >> 2, q = t & 3;   // staging: 64 rows x 4 quads per pass, 2 passes
    for (int k0 = 0; k0 < K; k0 += 32) {
        __syncthreads();
        *(uint4*)&As[(r) * ASTR + q * 8] =
            *(const uint4*)(A + (size_t)(m0 + r) * K + k0 + q * 8);
        *(uint4*)&As[(r + 64) * ASTR + q * 8] =
            *(const uint4*)(A + (size_t)(m0 + r + 64) * K + k0 + q * 8);
        *(uint4*)&Bs[(r) * ASTR + q * 8] =
            *(const uint4*)(Bt + (size_t)(n0 + r) * K + k0 + q * 8);
        *(uint4*)&Bs[(r + 64) * ASTR + q * 8] =
            *(const uint4*)(Bt + (size_t)(n0 + r + 64) * K + k0 + q * 8);
        __syncthreads();
        short8 af[4], bfr[4];
#pragma unroll
        for (int i = 0; i < 4; ++i)
            af[i] = *(const short8*)&As[(wr * 64 + i * 16 + lrow) * ASTR + quad * 8];
#pragma unroll
        for (int j = 0; j < 4; ++j)
            bfr[j] = *(const short8*)&Bs[(wc * 64 + j * 16 + lrow) * ASTR + quad * 8];
#pragma unroll
        for (int i = 0; i < 4; ++i)
#pragma unroll
            for (int j = 0; j < 4; ++j)
                acc[i][j] = __builtin_amdgcn_mfma_f32_16x16x32_bf16(af[i], bfr[j],
                                                                    acc[i][j], 0, 0, 0);
    }
#pragma unroll
    for (int i = 0; i < 4; ++i) {
#pragma unroll
        for (int j = 0; j < 4; ++j) {
            int n = n0 + wc * 64 + j * 16 + lrow;
            float bv = bias[n];
#pragma unroll
            for (int rg = 0; rg < 4; ++rg) {
                int m = m0 + wr * 64 + i * 16 + quad * 4 + rg;
                float v = acc[i][j][rg] + bv;
                if (C32) C32[(size_t)m * HIDDEN + n] = v;
                C16[(size_t)m * HIDDEN + n] = f2bf(v);
            }
        }
    }
}

// ---------- per-node attention scores from bf16 hp ----------
__global__ __launch_bounds__(256) void scores_kernel(const ushort* __restrict__ hpb,
                                                     const float* __restrict__ a_s,
                                                     const float* __restrict__ a_d,
                                                     float* __restrict__ s_src,
                                                     float* __restrict__ s_dst) {
    int n = blockIdx.x;
    int c = threadIdx.x;
    int w = c >> 6, lane = c & 63;
    float v = bf2f(hpb[(size_t)n * HIDDEN + c]);
    float ps = waveReduceSum(v * a_s[c]);
    float pd = waveReduceSum(v * a_d[c]);
    if (lane == 0) {
        s_src[n * 4 + w] = ps;
        s_dst[n * 4 + w] = pd;
    }
}

// ---------- per-edge logits + segment max ----------
__global__ __launch_bounds__(256) void edge_logits(const int* __restrict__ src,
                                                   const int* __restrict__ dst,
                                                   const float* __restrict__ ea,
                                                   const float* __restrict__ s_src,
                                                   const float* __restrict__ s_dst,
                                                   const float* __restrict__ w_ea,
                                                   float* __restrict__ logit,
                                                   unsigned* __restrict__ mbuf, int E) {
    int e = blockIdx.x * blockDim.x + threadIdx.x;
    if (e >= E) return;
    int s = src[e], d = dst[e];
    float4 ss = *(const float4*)(s_src + (size_t)s * 4);
    float4 sd = *(const float4*)(s_dst + (size_t)d * 4);
    float e0 = ea[(size_t)e * 3], e1 = ea[(size_t)e * 3 + 1], e2 = ea[(size_t)e * 3 + 2];
    float ssv[4] = {ss.x, ss.y, ss.z, ss.w};
    float sdv[4] = {sd.x, sd.y, sd.z, sd.w};
#pragma unroll
    for (int h = 0; h < 4; ++h) {
        float esc = e0 * w_ea[h * 3] + e1 * w_ea[h * 3 + 1] + e2 * w_ea[h * 3 + 2];
        float lg = ssv[h] + sdv[h] + esc;
        lg = lg > 0.f ? lg : NEG_SLOPE * lg;
        logit[(size_t)e * 4 + h] = lg;
        atomicMax(&mbuf[d * 4 + h], mapf(lg));
    }
}

// ---------- per-node aggregation (CSR) from bf16 hp; fp32 residual stream ----------
__global__ __launch_bounds__(256) void aggregate(const int* __restrict__ rowptr,
                                                 const int* __restrict__ eid,
                                                 const int* __restrict__ src,
                                                 const float* __restrict__ logit,
                                                 const unsigned* __restrict__ mbuf,
                                                 const ushort* __restrict__ hpb,
                                                 const float* __restrict__ h_in,
                                                 float* __restrict__ h_out,
                                                 ushort* __restrict__ h_out_bf) {
    int n = blockIdx.x;
    int c = threadIdx.x;
    int h = c >> 6;
    float mh = unmapf(mbuf[n * 4 + h]);
    int beg = rowptr[n], end = rowptr[n + 1];
    float acc = 0.f, dsum = 0.f;
    int e = 0, s = 0;
    if (beg < end) { e = eid[beg]; s = src[e]; }
    for (int i = beg; i < end; ++i) {
        int ec = e, sc = s;
        if (i + 1 < end) { e = eid[i + 1]; s = src[e]; }   // prefetch next indices
        float lg = logit[(size_t)ec * 4 + h];
        float v = bf2f(hpb[(size_t)sc * HIDDEN + c]);
        float ex = __expf(lg - mh);
        dsum += ex;
        acc = fmaf(v, ex, acc);
    }
    float out = acc / fmaxf(dsum, 1e-16f);
    float y = elu_f(out + h_in[(size_t)n * HIDDEN + c]);
    h_out[(size_t)n * HIDDEN + c] = y;
    h_out_bf[(size_t)n * HIDDEN + c] = f2bf(y);
}

// ---------- parallel pool: run-accumulate over sorted batch, atomic flush ----------
__global__ __launch_bounds__(256) void pool_partial(const float* __restrict__ nemb,
                                                    const int* __restrict__ batch,
                                                    float* __restrict__ gout, int N) {
    int r0 = blockIdx.x * 128;
    int c = threadIdx.x;
    __shared__ int bsh[128];
    if (c < 128) {
        int r = r0 + c;
        bsh[c] = (r < N) ? batch[r] : -1;
    }
    __syncthreads();
    int rend = min(128, N - r0);
    float acc = 0.f;
    int cur = bsh[0];
    for (int i = 0; i < rend; ++i) {
        int g = bsh[i];
        if (g != cur) {
            atomicAdd(&gout[cur * HIDDEN + c], acc);
            acc = 0.f;
            cur = g;
        }
        acc += nemb[(size_t)(r0 + i) * HIDDEN + c];
    }
    if (cur >= 0) atomicAdd(&gout[cur * HIDDEN + c], acc);
}

__global__ void count_kernel(const int* __restrict__ batch, int* __restrict__ cnt, int N) {
    int g = threadIdx.x;
    if (g >= NUM_GRAPHS) return;
    int lo = 0, hi = N;
    while (lo < hi) { int mid = (lo + hi) >> 1; if (batch[mid] < g) lo = mid + 1; else hi = mid; }
    int start = lo;
    lo = start; hi = N;
    while (lo < hi) { int mid = (lo + hi) >> 1; if (batch[mid] < g + 1) lo = mid + 1; else hi = mid; }
    cnt[g] = lo - start;
}

__global__ void pool_div(float* __restrict__ gout, const int* __restrict__ cnt) {
    int g = blockIdx.x;
    int c = threadIdx.x;
    gout[g * HIDDEN + c] /= fmaxf((float)cnt[g], 1.f);
}

extern "C" void kernel_launch(void* const* d_in, const int* in_sizes, int n_in,
                              void* d_out, int out_size, void* d_ws, size_t ws_size,
                              hipStream_t stream) {
    const float* x       = (const float*)d_in[0];
    const int*   ei      = (const int*)d_in[1];
    const float* ea      = (const float*)d_in[2];
    const int*   batch   = (const int*)d_in[3];
    const float* W_in    = (const float*)d_in[4];
    const float* b_in    = (const float*)d_in[5];
    const float* ln_in_g = (const float*)d_in[6];
    const float* ln_in_b = (const float*)d_in[7];
    const float* W_gat   = (const float*)d_in[8];
    const float* b_gat   = (const float*)d_in[9];
    const float* W_e     = (const float*)d_in[10];
    const float* a_src   = (const float*)d_in[11];
    const float* a_dst   = (const float*)d_in[12];
    const float* a_edge  = (const float*)d_in[13];
    const float* W_out   = (const float*)d_in[14];
    const float* b_out   = (const float*)d_in[15];
    const float* ln_out_g= (const float*)d_in[16];
    const float* ln_out_b= (const float*)d_in[17];

    int N = in_sizes[0] / 8;
    int E = in_sizes[1] / 2;
    int Mpad = (N + 127) & ~127;
    const int* srcA = ei;
    const int* dstA = ei + E;

    char* w = (char*)d_ws;
    size_t off = 0;
    auto alloc = [&](size_t bytes) {
        void* p = w + off;
        off += (bytes + 255) & ~(size_t)255;
        return p;
    };
    float*    hA     = (float*)alloc((size_t)Mpad * HIDDEN * 4);   // fp32 residual A / final hp
    float*    hB     = (float*)alloc((size_t)Mpad * HIDDEN * 4);   // fp32 residual B
    ushort*   hAb    = (ushort*)alloc((size_t)Mpad * HIDDEN * 2);  // bf16 mirror of hA
    ushort*   hBb    = (ushort*)alloc((size_t)Mpad * HIDDEN * 2);
    ushort*   hpb    = (ushort*)alloc((size_t)Mpad * HIDDEN * 2);  // bf16 GEMM output
    float*    sSrc   = (float*)alloc((size_t)N * 4 * 4);
    float*    sDst   = (float*)alloc((size_t)N * 4 * 4);
    float*    logit  = (float*)alloc((size_t)E * 4 * 4);
    unsigned* mbuf   = (unsigned*)alloc((size_t)N * 4 * 4);
    int*      deg    = (int*)alloc((size_t)N * 4);
    int*      rowptr = (int*)alloc((size_t)(N + 1) * 4);
    int*      nxt    = (int*)alloc((size_t)N * 4);
    int*      eid    = (int*)alloc((size_t)E * 4);
    float*    wea    = (float*)alloc(64 * 4);
    ushort*   Wt     = (ushort*)alloc((size_t)4 * HIDDEN * HIDDEN * 2);
    int*      cnt    = (int*)alloc(NUM_GRAPHS * 4);

    // --- CSR by dst + weight prep (inputs restored before every call) ---
    hipMemsetAsync(deg, 0, (size_t)N * 4, stream);
    hist_kernel<<<(E + 255) / 256, 256, 0, stream>>>(dstA, deg, E);
    scan_kernel<<<1, 256, 0, stream>>>(deg, rowptr, N, E);
    copy_int<<<(N + 255) / 256, 256, 0, stream>>>(rowptr, nxt, N);
    scatter_kernel<<<(E + 255) / 256, 256, 0, stream>>>(dstA, nxt, eid, E);
    wea_kernel<<<1, 64, 0, stream>>>(W_e, a_edge, wea);
    conv_w<<<dim3(4, HIDDEN), 256, 0, stream>>>(W_gat, W_out, Wt);

    // --- input projection + LN + ELU ---
    inproj_ln<<<N, 256, 0, stream>>>(x, W_in, b_in, ln_in_g, ln_in_b, hA, hAb);

    float* hcur = hA;   ushort* hcurb = hAb;
    float* hnext = hB;  ushort* hnextb = hBb;
    dim3 gg(Mpad / 128, HIDDEN / 128);
    for (int l = 0; l < LAYERS; ++l) {
        gemm_mfma<<<gg, 256, 0, stream>>>(hcurb, Wt + (size_t)l * HIDDEN * HIDDEN,
                                          b_gat + l * HIDDEN, nullptr, hpb, Mpad);
        scores_kernel<<<N, 256, 0, stream>>>(hpb, a_src + l * HIDDEN, a_dst + l * HIDDEN,
                                             sSrc, sDst);
        hipMemsetAsync(mbuf, 0, (size_t)N * 16, stream);
        edge_logits<<<(E + 255) / 256, 256, 0, stream>>>(srcA, dstA, ea, sSrc, sDst,
                                                         wea + l * 12, logit, mbuf, E);
        aggregate<<<N, 256, 0, stream>>>(rowptr, eid, srcA, logit, mbuf, hpb,
                                         hcur, hnext, hnextb);
        float* tf = hcur; hcur = hnext; hnext = tf;
        ushort* tb = hcurb; hcurb = hnextb; hnextb = tb;
    }

    // --- output projection (fp32 out into the free fp32 buffer) + LN + pool ---
    float* hp32 = hnext;   // the buffer NOT holding the final residual stream
    gemm_mfma<<<gg, 256, 0, stream>>>(hcurb, Wt + (size_t)3 * HIDDEN * HIDDEN,
                                      b_out, hp32, hpb, Mpad);
    float* gout = (float*)d_out;
    float* nemb = gout + (size_t)NUM_GRAPHS * HIDDEN;
    ln_elu<<<N, 256, 0, stream>>>(hp32, ln_out_g, ln_out_b, nemb);
    hipMemsetAsync(gout, 0, (size_t)NUM_GRAPHS * HIDDEN * 4, stream);
    pool_partial<<<(N + 127) / 128, 256, 0, stream>>>(nemb, batch, gout, N);
    count_kernel<<<1, 64, 0, stream>>>(batch, cnt, N);
    pool_div<<<NUM_GRAPHS, 256, 0, stream>>>(gout, cnt);
}

// Round 3
// 885.639 us; speedup vs baseline: 2.7310x; 1.8243x over previous
//
#include <hip/hip_runtime.h>
#include <math.h>

#define HIDDEN 256
#define HEADS 4
#define HEAD_DIM 64
#define LAYERS 3
#define NUM_GRAPHS 64
#define NEG_SLOPE 0.2f

typedef short short8 __attribute__((ext_vector_type(8)));
typedef float floatx4 __attribute__((ext_vector_type(4)));

// ---------- helpers ----------
static __device__ __forceinline__ float elu_f(float x) {
    return x > 0.f ? x : expm1f(x);
}

static __device__ __forceinline__ float waveReduceSum(float v) {
#pragma unroll
    for (int off = 32; off > 0; off >>= 1) v += __shfl_xor(v, off, 64);
    return v;
}

// fp32 <-> bf16 (RNE)
static __device__ __forceinline__ ushort f2bf(float f) {
    unsigned u = __float_as_uint(f);
    unsigned r = (u + 0x7FFFu + ((u >> 16) & 1u)) >> 16;
    return (ushort)r;
}
static __device__ __forceinline__ float bf2f(ushort h) {
    return __uint_as_float(((unsigned)h) << 16);
}

// ---------- CSR build ----------
__global__ void hist_kernel(const int* __restrict__ dst, int* __restrict__ deg, int E) {
    int e = blockIdx.x * blockDim.x + threadIdx.x;
    if (e < E) atomicAdd(&deg[dst[e]], 1);
}

__global__ void scan_kernel(const int* __restrict__ deg, int* __restrict__ rowptr, int N, int E) {
    __shared__ int part[256];
    __shared__ int offs[256];
    int t = threadIdx.x;
    int chunk = (N + 255) / 256;
    int b0 = t * chunk;
    int b1 = min(b0 + chunk, N);
    int s = 0;
    for (int i = b0; i < b1; ++i) s += deg[i];
    part[t] = s;
    __syncthreads();
    if (t == 0) {
        int run = 0;
        for (int i = 0; i < 256; ++i) { offs[i] = run; run += part[i]; }
    }
    __syncthreads();
    int run = offs[t];
    for (int i = b0; i < b1; ++i) { rowptr[i] = run; run += deg[i]; }
    if (t == 0) rowptr[N] = E;
}

__global__ void copy_int(const int* __restrict__ a, int* __restrict__ b, int n) {
    int i = blockIdx.x * blockDim.x + threadIdx.x;
    if (i < n) b[i] = a[i];
}

// scatter: CSR-order per-edge metadata. smeta[slot]=src node;
// esc_l[l][slot*4+h] = ea[e,:] . wea[l,h,:]  (edge-score contribution, layer-static)
__global__ void scatter_kernel(const int* __restrict__ src, const int* __restrict__ dst,
                               const float* __restrict__ ea, const float* __restrict__ wea,
                               int* __restrict__ nxt, int* __restrict__ smeta,
                               float* __restrict__ esc0, float* __restrict__ esc1,
                               float* __restrict__ esc2, int E) {
    int e = blockIdx.x * blockDim.x + threadIdx.x;
    if (e >= E) return;
    int d = dst[e];
    int slot = atomicAdd(&nxt[d], 1);
    smeta[slot] = src[e];
    float e0 = ea[(size_t)e * 3], e1 = ea[(size_t)e * 3 + 1], e2 = ea[(size_t)e * 3 + 2];
    float* escs[3] = {esc0, esc1, esc2};
#pragma unroll
    for (int l = 0; l < 3; ++l) {
        float4 v;
        float* vp = (float*)&v;
#pragma unroll
        for (int h = 0; h < 4; ++h) {
            const float* w = wea + l * 12 + h * 3;
            vp[h] = e0 * w[0] + e1 * w[1] + e2 * w[2];
        }
        *(float4*)(escs[l] + (size_t)slot * 4) = v;
    }
}

// ---------- tiny precompute: w_ea[l][h][k] = sum_d We[l,k,h*64+d] * a_e[l,h,d] ----------
__global__ void wea_kernel(const float* __restrict__ We, const float* __restrict__ a_e,
                           float* __restrict__ w_ea) {
    int t = threadIdx.x;
    if (t < LAYERS * HEADS * 3) {
        int l = t / 12, r = t % 12, h = r / 3, k = r % 3;
        float s = 0.f;
        for (int d = 0; d < HEAD_DIM; ++d)
            s += We[l * 3 * HIDDEN + k * HIDDEN + h * HEAD_DIM + d] *
                 a_e[l * HIDDEN + h * HEAD_DIM + d];
        w_ea[t] = s;
    }
}

// ---------- weight convert+transpose: Wt[l][n][k] = bf16(W_l[k][n]) ----------
__global__ void conv_w(const float* __restrict__ Wg, const float* __restrict__ Wo,
                       ushort* __restrict__ Wt) {
    int l = blockIdx.x;      // 0..3  (0..2 = GAT layers, 3 = W_out)
    int n = blockIdx.y;      // 0..255
    int k = threadIdx.x;     // 0..255
    const float* W = (l < 3) ? (Wg + (size_t)l * HIDDEN * HIDDEN) : Wo;
    Wt[(size_t)l * HIDDEN * HIDDEN + (size_t)n * HIDDEN + k] =
        f2bf(W[(size_t)k * HIDDEN + n]);
}

// ---------- input projection + LayerNorm + ELU (fp32 + bf16 outputs) ----------
__global__ __launch_bounds__(256) void inproj_ln(const float* __restrict__ x,
                                                 const float* __restrict__ W,
                                                 const float* __restrict__ b,
                                                 const float* __restrict__ g,
                                                 const float* __restrict__ beta,
                                                 float* __restrict__ h,
                                                 ushort* __restrict__ hb) {
    int n = blockIdx.x;
    int c = threadIdx.x;
    float acc = b[c];
#pragma unroll
    for (int k = 0; k < 8; ++k) acc += x[n * 8 + k] * W[k * HIDDEN + c];
    __shared__ float red[8];
    float s = waveReduceSum(acc);
    float s2 = waveReduceSum(acc * acc);
    int w = c >> 6;
    if ((c & 63) == 0) { red[w] = s; red[4 + w] = s2; }
    __syncthreads();
    float mu = (red[0] + red[1] + red[2] + red[3]) * (1.f / 256.f);
    float ms = (red[4] + red[5] + red[6] + red[7]) * (1.f / 256.f);
    float inv = rsqrtf(ms - mu * mu + 1e-5f);
    float y = elu_f((acc - mu) * inv * g[c] + beta[c]);
    h[(size_t)n * HIDDEN + c] = y;
    hb[(size_t)n * HIDDEN + c] = f2bf(y);
}

// ---------- LayerNorm + ELU (final, fp32 input) ----------
__global__ __launch_bounds__(256) void ln_elu(const float* __restrict__ t,
                                              const float* __restrict__ g,
                                              const float* __restrict__ beta,
                                              float* __restrict__ out) {
    int n = blockIdx.x;
    int c = threadIdx.x;
    float acc = t[(size_t)n * HIDDEN + c];
    __shared__ float red[8];
    float s = waveReduceSum(acc);
    float s2 = waveReduceSum(acc * acc);
    int w = c >> 6;
    if ((c & 63) == 0) { red[w] = s; red[4 + w] = s2; }
    __syncthreads();
    float mu = (red[0] + red[1] + red[2] + red[3]) * (1.f / 256.f);
    float ms = (red[4] + red[5] + red[6] + red[7]) * (1.f / 256.f);
    float inv = rsqrtf(ms - mu * mu + 1e-5f);
    float y = (acc - mu) * inv * g[c] + beta[c];
    out[(size_t)n * HIDDEN + c] = elu_f(y);
}

// ---------- bf16 MFMA GEMM + fused per-node attention scores ----------
// C[M,256] = A[M,256] @ Bt[n][k]^T + bias.  128x128 tile, 4 waves 2x2, each
// wave 64x64 via 4x4 mfma_16x16x32.  C/D: col=lane&15, row=(lane>>4)*4+reg.
// Each wave's 64 n-columns = exactly one head => unique writer for
// s_src[m,h] / s_dst[m,h]: 16-lane shfl reduce + plain store (no atomics).
#define ASTR 40   // padded LDS row stride (ushorts)
__global__ __launch_bounds__(256) void gemm_mfma(const ushort* __restrict__ A,
                                                 const ushort* __restrict__ Bt,
                                                 const float* __restrict__ bias,
                                                 float* __restrict__ C32,
                                                 ushort* __restrict__ C16,
                                                 const float* __restrict__ a_s,
                                                 const float* __restrict__ a_d,
                                                 float* __restrict__ s_src,
                                                 float* __restrict__ s_dst,
                                                 int doScore) {
    const int K = 256;
    __shared__ ushort As[128 * ASTR];
    __shared__ ushort Bs[128 * ASTR];
    int m0 = blockIdx.x * 128;
    int n0 = blockIdx.y * 128;
    int t = threadIdx.x;
    int wave = t >> 6, lane = t & 63;
    int wr = wave >> 1, wc = wave & 1;
    int lrow = lane & 15;
    int quad = lane >> 4;
    floatx4 acc[4][4] = {};
    int r = t >> 2, q = t & 3;
    for (int k0 = 0; k0 < K; k0 += 32) {
        __syncthreads();
        *(uint4*)&As[(r) * ASTR + q * 8] =
            *(const uint4*)(A + (size_t)(m0 + r) * K + k0 + q * 8);
        *(uint4*)&As[(r + 64) * ASTR + q * 8] =
            *(const uint4*)(A + (size_t)(m0 + r + 64) * K + k0 + q * 8);
        *(uint4*)&Bs[(r) * ASTR + q * 8] =
            *(const uint4*)(Bt + (size_t)(n0 + r) * K + k0 + q * 8);
        *(uint4*)&Bs[(r + 64) * ASTR + q * 8] =
            *(const uint4*)(Bt + (size_t)(n0 + r + 64) * K + k0 + q * 8);
        __syncthreads();
        short8 af[4], bfr[4];
#pragma unroll
        for (int i = 0; i < 4; ++i)
            af[i] = *(const short8*)&As[(wr * 64 + i * 16 + lrow) * ASTR + quad * 8];
#pragma unroll
        for (int j = 0; j < 4; ++j)
            bfr[j] = *(const short8*)&Bs[(wc * 64 + j * 16 + lrow) * ASTR + quad * 8];
#pragma unroll
        for (int i = 0; i < 4; ++i)
#pragma unroll
            for (int j = 0; j < 4; ++j)
                acc[i][j] = __builtin_amdgcn_mfma_f32_16x16x32_bf16(af[i], bfr[j],
                                                                    acc[i][j], 0, 0, 0);
    }
    int hh = (n0 + wc * 64) >> 6;
    int ncol[4];
    float bv4[4], asv[4], adv[4];
#pragma unroll
    for (int j = 0; j < 4; ++j) {
        int n = n0 + wc * 64 + j * 16 + lrow;
        ncol[j] = n;
        bv4[j] = bias[n];
        asv[j] = a_s[n];
        adv[j] = a_d[n];
    }
#pragma unroll
    for (int i = 0; i < 4; ++i) {
#pragma unroll
        for (int rg = 0; rg < 4; ++rg) {
            int mrow = m0 + wr * 64 + i * 16 + quad * 4 + rg;
            float ps = 0.f, pd = 0.f;
#pragma unroll
            for (int j = 0; j < 4; ++j) {
                float v = acc[i][j][rg] + bv4[j];
                if (C32) C32[(size_t)mrow * HIDDEN + ncol[j]] = v;
                C16[(size_t)mrow * HIDDEN + ncol[j]] = f2bf(v);
                ps = fmaf(v, asv[j], ps);
                pd = fmaf(v, adv[j], pd);
            }
            if (doScore) {
#pragma unroll
                for (int off = 1; off < 16; off <<= 1) {
                    ps += __shfl_xor(ps, off, 64);
                    pd += __shfl_xor(pd, off, 64);
                }
                if (lrow == 0) {
                    s_src[mrow * 4 + hh] = ps;
                    s_dst[mrow * 4 + hh] = pd;
                }
            }
        }
    }
}

// ---------- wave-per-node aggregation with online softmax ----------
// 4 nodes/block (1 wave each). Lane l owns channels 4l..4l+3 (ushort4 loads).
// Online max/rescale removes the separate edge_logits pass + logit buffer.
#define AGG_STEP(LG, V)                                                        \
    {                                                                          \
        float mn = fmaxf(m, (LG));                                             \
        float scl = __expf(m - mn);                                            \
        float ex = __expf((LG) - mn);                                          \
        m = mn;                                                                \
        dsum = fmaf(dsum, scl, ex);                                            \
        a0 = fmaf(a0, scl, bf2f((V).x) * ex);                                  \
        a1 = fmaf(a1, scl, bf2f((V).y) * ex);                                  \
        a2 = fmaf(a2, scl, bf2f((V).z) * ex);                                  \
        a3 = fmaf(a3, scl, bf2f((V).w) * ex);                                  \
    }

#define AGG_FETCH(IDX, LG, V)                                                  \
    {                                                                          \
        int s_ = smeta[beg + (IDX)];                                           \
        float lgv_ = sdn + s_src[s_ * 4 + h] + escl[(size_t)(beg + (IDX)) * 4 + h]; \
        (LG) = lgv_ > 0.f ? lgv_ : NEG_SLOPE * lgv_;                           \
        (V) = *(const ushort4*)(hpb + (size_t)s_ * HIDDEN + c0);               \
    }

__global__ __launch_bounds__(256) void aggregate(const int* __restrict__ rowptr,
                                                 const int* __restrict__ smeta,
                                                 const float* __restrict__ escl,
                                                 const float* __restrict__ s_src,
                                                 const float* __restrict__ s_dst,
                                                 const ushort* __restrict__ hpb,
                                                 const float* __restrict__ h_in,
                                                 float* __restrict__ h_out,
                                                 ushort* __restrict__ h_out_bf,
                                                 int N) {
    int wv = threadIdx.x >> 6;
    int n = blockIdx.x * 4 + wv;
    if (n >= N) return;
    int l = threadIdx.x & 63;
    int h = l >> 4;
    int c0 = l * 4;
    float sdn = s_dst[n * 4 + h];
    int beg = rowptr[n];
    int cnt = rowptr[n + 1] - beg;
    float m = -1e30f, dsum = 0.f, a0 = 0.f, a1 = 0.f, a2 = 0.f, a3 = 0.f;
    float lg0, lg1;
    ushort4 v0, v1;
    if (cnt > 0) AGG_FETCH(0, lg0, v0);
    if (cnt > 1) AGG_FETCH(1, lg1, v1);
    int i = 0;
    while (i < cnt) {
        AGG_STEP(lg0, v0);
        if (i + 2 < cnt) AGG_FETCH(i + 2, lg0, v0);
        ++i;
        if (i >= cnt) break;
        AGG_STEP(lg1, v1);
        if (i + 2 < cnt) AGG_FETCH(i + 2, lg1, v1);
        ++i;
    }
    float inv = 1.f / fmaxf(dsum, 1e-16f);
    float4 hi = *(const float4*)(h_in + (size_t)n * HIDDEN + c0);
    float y0 = elu_f(fmaf(a0, inv, hi.x));
    float y1 = elu_f(fmaf(a1, inv, hi.y));
    float y2 = elu_f(fmaf(a2, inv, hi.z));
    float y3 = elu_f(fmaf(a3, inv, hi.w));
    float4 yo = {y0, y1, y2, y3};
    *(float4*)(h_out + (size_t)n * HIDDEN + c0) = yo;
    ushort4 yb = {f2bf(y0), f2bf(y1), f2bf(y2), f2bf(y3)};
    *(ushort4*)(h_out_bf + (size_t)n * HIDDEN + c0) = yb;
}

// ---------- parallel pool ----------
__global__ __launch_bounds__(256) void pool_partial(const float* __restrict__ nemb,
                                                    const int* __restrict__ batch,
                                                    float* __restrict__ gout, int N) {
    int r0 = blockIdx.x * 128;
    int c = threadIdx.x;
    __shared__ int bsh[128];
    if (c < 128) {
        int r = r0 + c;
        bsh[c] = (r < N) ? batch[r] : -1;
    }
    __syncthreads();
    int rend = min(128, N - r0);
    float acc = 0.f;
    int cur = bsh[0];
    for (int i = 0; i < rend; ++i) {
        int g = bsh[i];
        if (g != cur) {
            atomicAdd(&gout[cur * HIDDEN + c], acc);
            acc = 0.f;
            cur = g;
        }
        acc += nemb[(size_t)(r0 + i) * HIDDEN + c];
    }
    if (cur >= 0) atomicAdd(&gout[cur * HIDDEN + c], acc);
}

__global__ void count_kernel(const int* __restrict__ batch, int* __restrict__ cnt, int N) {
    int g = threadIdx.x;
    if (g >= NUM_GRAPHS) return;
    int lo = 0, hi = N;
    while (lo < hi) { int mid = (lo + hi) >> 1; if (batch[mid] < g) lo = mid + 1; else hi = mid; }
    int start = lo;
    lo = start; hi = N;
    while (lo < hi) { int mid = (lo + hi) >> 1; if (batch[mid] < g + 1) lo = mid + 1; else hi = mid; }
    cnt[g] = lo - start;
}

__global__ void pool_div(float* __restrict__ gout, const int* __restrict__ cnt) {
    int g = blockIdx.x;
    int c = threadIdx.x;
    gout[g * HIDDEN + c] /= fmaxf((float)cnt[g], 1.f);
}

extern "C" void kernel_launch(void* const* d_in, const int* in_sizes, int n_in,
                              void* d_out, int out_size, void* d_ws, size_t ws_size,
                              hipStream_t stream) {
    const float* x       = (const float*)d_in[0];
    const int*   ei      = (const int*)d_in[1];
    const float* ea      = (const float*)d_in[2];
    const int*   batch   = (const int*)d_in[3];
    const float* W_in    = (const float*)d_in[4];
    const float* b_in    = (const float*)d_in[5];
    const float* ln_in_g = (const float*)d_in[6];
    const float* ln_in_b = (const float*)d_in[7];
    const float* W_gat   = (const float*)d_in[8];
    const float* b_gat   = (const float*)d_in[9];
    const float* W_e     = (const float*)d_in[10];
    const float* a_src   = (const float*)d_in[11];
    const float* a_dst   = (const float*)d_in[12];
    const float* a_edge  = (const float*)d_in[13];
    const float* W_out   = (const float*)d_in[14];
    const float* b_out   = (const float*)d_in[15];
    const float* ln_out_g= (const float*)d_in[16];
    const float* ln_out_b= (const float*)d_in[17];

    int N = in_sizes[0] / 8;
    int E = in_sizes[1] / 2;
    int Mpad = (N + 127) & ~127;
    const int* srcA = ei;
    const int* dstA = ei + E;

    char* w = (char*)d_ws;
    size_t off = 0;
    auto alloc = [&](size_t bytes) {
        void* p = w + off;
        off += (bytes + 255) & ~(size_t)255;
        return p;
    };
    float*    hA     = (float*)alloc((size_t)Mpad * HIDDEN * 4);
    float*    hB     = (float*)alloc((size_t)Mpad * HIDDEN * 4);
    ushort*   hAb    = (ushort*)alloc((size_t)Mpad * HIDDEN * 2);
    ushort*   hBb    = (ushort*)alloc((size_t)Mpad * HIDDEN * 2);
    ushort*   hpb    = (ushort*)alloc((size_t)Mpad * HIDDEN * 2);
    float*    sSrc   = (float*)alloc((size_t)Mpad * 4 * 4);
    float*    sDst   = (float*)alloc((size_t)Mpad * 4 * 4);
    int*      deg    = (int*)alloc((size_t)N * 4);
    int*      rowptr = (int*)alloc((size_t)(N + 1) * 4);
    int*      nxt    = (int*)alloc((size_t)N * 4);
    int*      smeta  = (int*)alloc((size_t)E * 4);
    float*    esc0   = (float*)alloc((size_t)E * 4 * 4);
    float*    esc1   = (float*)alloc((size_t)E * 4 * 4);
    float*    esc2   = (float*)alloc((size_t)E * 4 * 4);
    float*    wea    = (float*)alloc(64 * 4);
    ushort*   Wt     = (ushort*)alloc((size_t)4 * HIDDEN * HIDDEN * 2);
    int*      cnt    = (int*)alloc(NUM_GRAPHS * 4);
    float*    escs[3] = {esc0, esc1, esc2};

    // --- CSR by dst + per-edge static metadata + weight prep ---
    hipMemsetAsync(deg, 0, (size_t)N * 4, stream);
    hist_kernel<<<(E + 255) / 256, 256, 0, stream>>>(dstA, deg, E);
    scan_kernel<<<1, 256, 0, stream>>>(deg, rowptr, N, E);
    copy_int<<<(N + 255) / 256, 256, 0, stream>>>(rowptr, nxt, N);
    wea_kernel<<<1, 64, 0, stream>>>(W_e, a_edge, wea);
    scatter_kernel<<<(E + 255) / 256, 256, 0, stream>>>(srcA, dstA, ea, wea, nxt,
                                                        smeta, esc0, esc1, esc2, E);
    conv_w<<<dim3(4, HIDDEN), 256, 0, stream>>>(W_gat, W_out, Wt);

    // --- input projection + LN + ELU ---
    inproj_ln<<<N, 256, 0, stream>>>(x, W_in, b_in, ln_in_g, ln_in_b, hA, hAb);

    float* hcur = hA;   ushort* hcurb = hAb;
    float* hnext = hB;  ushort* hnextb = hBb;
    dim3 gg(Mpad / 128, HIDDEN / 128);
    for (int l = 0; l < LAYERS; ++l) {
        gemm_mfma<<<gg, 256, 0, stream>>>(hcurb, Wt + (size_t)l * HIDDEN * HIDDEN,
                                          b_gat + l * HIDDEN, nullptr, hpb,
                                          a_src + l * HIDDEN, a_dst + l * HIDDEN,
                                          sSrc, sDst, 1);
        aggregate<<<(N + 3) / 4, 256, 0, stream>>>(rowptr, smeta, escs[l], sSrc, sDst,
                                                   hpb, hcur, hnext, hnextb, N);
        float* tf = hcur; hcur = hnext; hnext = tf;
        ushort* tb = hcurb; hcurb = hnextb; hnextb = tb;
    }

    // --- output projection + LN + pool ---
    float* hp32 = hnext;   // buffer NOT holding the final residual stream
    gemm_mfma<<<gg, 256, 0, stream>>>(hcurb, Wt + (size_t)3 * HIDDEN * HIDDEN,
                                      b_out, hp32, hpb, a_src, a_dst, sSrc, sDst, 0);
    float* gout = (float*)d_out;
    float* nemb = gout + (size_t)NUM_GRAPHS * HIDDEN;
    ln_elu<<<N, 256, 0, stream>>>(hp32, ln_out_g, ln_out_b, nemb);
    hipMemsetAsync(gout, 0, (size_t)NUM_GRAPHS * HIDDEN * 4, stream);
    pool_partial<<<(N + 127) / 128, 256, 0, stream>>>(nemb, batch, gout, N);
    count_kernel<<<1, 64, 0, stream>>>(batch, cnt, N);
    pool_div<<<NUM_GRAPHS, 256, 0, stream>>>(gout, cnt);
}

// Round 4
// 849.210 us; speedup vs baseline: 2.8481x; 1.0429x over previous
//
#include <hip/hip_runtime.h>
#include <math.h>

#define HIDDEN 256
#define HEADS 4
#define HEAD_DIM 64
#define LAYERS 3
#define NUM_GRAPHS 64
#define NEG_SLOPE 0.2f

typedef short short8 __attribute__((ext_vector_type(8)));
typedef float floatx4 __attribute__((ext_vector_type(4)));

// ---------- helpers ----------
static __device__ __forceinline__ float elu_f(float x) {
    return x > 0.f ? x : expm1f(x);
}

static __device__ __forceinline__ float waveReduceSum(float v) {
#pragma unroll
    for (int off = 32; off > 0; off >>= 1) v += __shfl_xor(v, off, 64);
    return v;
}

// fp32 <-> bf16 (RNE)
static __device__ __forceinline__ ushort f2bf(float f) {
    unsigned u = __float_as_uint(f);
    unsigned r = (u + 0x7FFFu + ((u >> 16) & 1u)) >> 16;
    return (ushort)r;
}
static __device__ __forceinline__ float bf2f(ushort h) {
    return __uint_as_float(((unsigned)h) << 16);
}

// ---------- CSR build ----------
__global__ void hist_kernel(const int* __restrict__ dst, int* __restrict__ deg, int E) {
    int e = blockIdx.x * blockDim.x + threadIdx.x;
    if (e < E) atomicAdd(&deg[dst[e]], 1);
}

// writes rowptr AND nxt (so no copy kernel needed)
__global__ void scan_kernel(const int* __restrict__ deg, int* __restrict__ rowptr,
                            int* __restrict__ nxt, int N, int E) {
    __shared__ int part[256];
    __shared__ int offs[256];
    int t = threadIdx.x;
    int chunk = (N + 255) / 256;
    int b0 = t * chunk;
    int b1 = min(b0 + chunk, N);
    int s = 0;
    for (int i = b0; i < b1; ++i) s += deg[i];
    part[t] = s;
    __syncthreads();
    if (t == 0) {
        int run = 0;
        for (int i = 0; i < 256; ++i) { offs[i] = run; run += part[i]; }
    }
    __syncthreads();
    int run = offs[t];
    for (int i = b0; i < b1; ++i) { rowptr[i] = run; nxt[i] = run; run += deg[i]; }
    if (t == 0) rowptr[N] = E;
}

// scatter: CSR-order per-edge metadata. smeta[slot]=src node;
// esc_l[l][slot*4+h] = ea[e,:] . wea[l,h,:]
__global__ void scatter_kernel(const int* __restrict__ src, const int* __restrict__ dst,
                               const float* __restrict__ ea, const float* __restrict__ wea,
                               int* __restrict__ nxt, int* __restrict__ smeta,
                               float* __restrict__ esc0, float* __restrict__ esc1,
                               float* __restrict__ esc2, int E) {
    int e = blockIdx.x * blockDim.x + threadIdx.x;
    if (e >= E) return;
    int d = dst[e];
    int slot = atomicAdd(&nxt[d], 1);
    smeta[slot] = src[e];
    float e0 = ea[(size_t)e * 3], e1 = ea[(size_t)e * 3 + 1], e2 = ea[(size_t)e * 3 + 2];
    float* escs[3] = {esc0, esc1, esc2};
#pragma unroll
    for (int l = 0; l < 3; ++l) {
        float4 v;
        float* vp = (float*)&v;
#pragma unroll
        for (int h = 0; h < 4; ++h) {
            const float* w = wea + l * 12 + h * 3;
            vp[h] = e0 * w[0] + e1 * w[1] + e2 * w[2];
        }
        *(float4*)(escs[l] + (size_t)slot * 4) = v;
    }
}

// ---------- tiny precompute: w_ea[l][h][k] = sum_d We[l,k,h*64+d] * a_e[l,h,d] ----------
__global__ void wea_kernel(const float* __restrict__ We, const float* __restrict__ a_e,
                           float* __restrict__ w_ea) {
    int t = threadIdx.x;
    if (t < LAYERS * HEADS * 3) {
        int l = t / 12, r = t % 12, h = r / 3, k = r % 3;
        float s = 0.f;
        for (int d = 0; d < HEAD_DIM; ++d)
            s += We[l * 3 * HIDDEN + k * HIDDEN + h * HEAD_DIM + d] *
                 a_e[l * HIDDEN + h * HEAD_DIM + d];
        w_ea[t] = s;
    }
}

// ---------- weight convert+transpose: Wt[l][n][k] = bf16(W_l[k][n]) ----------
__global__ void conv_w(const float* __restrict__ Wg, const float* __restrict__ Wo,
                       ushort* __restrict__ Wt) {
    int l = blockIdx.x;
    int n = blockIdx.y;
    int k = threadIdx.x;
    const float* W = (l < 3) ? (Wg + (size_t)l * HIDDEN * HIDDEN) : Wo;
    Wt[(size_t)l * HIDDEN * HIDDEN + (size_t)n * HIDDEN + k] =
        f2bf(W[(size_t)k * HIDDEN + n]);
}

// ---------- input projection + LayerNorm + ELU (fp32 + bf16 outputs) ----------
__global__ __launch_bounds__(256) void inproj_ln(const float* __restrict__ x,
                                                 const float* __restrict__ W,
                                                 const float* __restrict__ b,
                                                 const float* __restrict__ g,
                                                 const float* __restrict__ beta,
                                                 float* __restrict__ h,
                                                 ushort* __restrict__ hb) {
    int n = blockIdx.x;
    int c = threadIdx.x;
    float acc = b[c];
#pragma unroll
    for (int k = 0; k < 8; ++k) acc += x[n * 8 + k] * W[k * HIDDEN + c];
    __shared__ float red[8];
    float s = waveReduceSum(acc);
    float s2 = waveReduceSum(acc * acc);
    int w = c >> 6;
    if ((c & 63) == 0) { red[w] = s; red[4 + w] = s2; }
    __syncthreads();
    float mu = (red[0] + red[1] + red[2] + red[3]) * (1.f / 256.f);
    float ms = (red[4] + red[5] + red[6] + red[7]) * (1.f / 256.f);
    float inv = rsqrtf(ms - mu * mu + 1e-5f);
    float y = elu_f((acc - mu) * inv * g[c] + beta[c]);
    h[(size_t)n * HIDDEN + c] = y;
    hb[(size_t)n * HIDDEN + c] = f2bf(y);
}

// ---------- LayerNorm + ELU (final, fp32 input) ----------
__global__ __launch_bounds__(256) void ln_elu(const float* __restrict__ t,
                                              const float* __restrict__ g,
                                              const float* __restrict__ beta,
                                              float* __restrict__ out) {
    int n = blockIdx.x;
    int c = threadIdx.x;
    float acc = t[(size_t)n * HIDDEN + c];
    __shared__ float red[8];
    float s = waveReduceSum(acc);
    float s2 = waveReduceSum(acc * acc);
    int w = c >> 6;
    if ((c & 63) == 0) { red[w] = s; red[4 + w] = s2; }
    __syncthreads();
    float mu = (red[0] + red[1] + red[2] + red[3]) * (1.f / 256.f);
    float ms = (red[4] + red[5] + red[6] + red[7]) * (1.f / 256.f);
    float inv = rsqrtf(ms - mu * mu + 1e-5f);
    float y = (acc - mu) * inv * g[c] + beta[c];
    out[(size_t)n * HIDDEN + c] = elu_f(y);
}

// ---------- bf16 MFMA GEMM + fused per-node attention scores ----------
#define ASTR 40
__global__ __launch_bounds__(256) void gemm_mfma(const ushort* __restrict__ A,
                                                 const ushort* __restrict__ Bt,
                                                 const float* __restrict__ bias,
                                                 float* __restrict__ C32,
                                                 ushort* __restrict__ C16,
                                                 const float* __restrict__ a_s,
                                                 const float* __restrict__ a_d,
                                                 float* __restrict__ s_src,
                                                 float* __restrict__ s_dst,
                                                 int doScore) {
    const int K = 256;
    __shared__ ushort As[128 * ASTR];
    __shared__ ushort Bs[128 * ASTR];
    int m0 = blockIdx.x * 128;
    int n0 = blockIdx.y * 128;
    int t = threadIdx.x;
    int wave = t >> 6, lane = t & 63;
    int wr = wave >> 1, wc = wave & 1;
    int lrow = lane & 15;
    int quad = lane >> 4;
    floatx4 acc[4][4] = {};
    int r = t >> 2, q = t & 3;
    for (int k0 = 0; k0 < K; k0 += 32) {
        __syncthreads();
        *(uint4*)&As[(r) * ASTR + q * 8] =
            *(const uint4*)(A + (size_t)(m0 + r) * K + k0 + q * 8);
        *(uint4*)&As[(r + 64) * ASTR + q * 8] =
            *(const uint4*)(A + (size_t)(m0 + r + 64) * K + k0 + q * 8);
        *(uint4*)&Bs[(r) * ASTR + q * 8] =
            *(const uint4*)(Bt + (size_t)(n0 + r) * K + k0 + q * 8);
        *(uint4*)&Bs[(r + 64) * ASTR + q * 8] =
            *(const uint4*)(Bt + (size_t)(n0 + r + 64) * K + k0 + q * 8);
        __syncthreads();
        short8 af[4], bfr[4];
#pragma unroll
        for (int i = 0; i < 4; ++i)
            af[i] = *(const short8*)&As[(wr * 64 + i * 16 + lrow) * ASTR + quad * 8];
#pragma unroll
        for (int j = 0; j < 4; ++j)
            bfr[j] = *(const short8*)&Bs[(wc * 64 + j * 16 + lrow) * ASTR + quad * 8];
#pragma unroll
        for (int i = 0; i < 4; ++i)
#pragma unroll
            for (int j = 0; j < 4; ++j)
                acc[i][j] = __builtin_amdgcn_mfma_f32_16x16x32_bf16(af[i], bfr[j],
                                                                    acc[i][j], 0, 0, 0);
    }
    int hh = (n0 + wc * 64) >> 6;
    int ncol[4];
    float bv4[4], asv[4], adv[4];
#pragma unroll
    for (int j = 0; j < 4; ++j) {
        int n = n0 + wc * 64 + j * 16 + lrow;
        ncol[j] = n;
        bv4[j] = bias[n];
        asv[j] = a_s[n];
        adv[j] = a_d[n];
    }
#pragma unroll
    for (int i = 0; i < 4; ++i) {
#pragma unroll
        for (int rg = 0; rg < 4; ++rg) {
            int mrow = m0 + wr * 64 + i * 16 + quad * 4 + rg;
            float ps = 0.f, pd = 0.f;
#pragma unroll
            for (int j = 0; j < 4; ++j) {
                float v = acc[i][j][rg] + bv4[j];
                if (C32) C32[(size_t)mrow * HIDDEN + ncol[j]] = v;
                C16[(size_t)mrow * HIDDEN + ncol[j]] = f2bf(v);
                ps = fmaf(v, asv[j], ps);
                pd = fmaf(v, adv[j], pd);
            }
            if (doScore) {
#pragma unroll
                for (int off = 1; off < 16; off <<= 1) {
                    ps += __shfl_xor(ps, off, 64);
                    pd += __shfl_xor(pd, off, 64);
                }
                if (lrow == 0) {
                    s_src[mrow * 4 + hh] = ps;
                    s_dst[mrow * 4 + hh] = pd;
                }
            }
        }
    }
}

// ---------- wave-per-node aggregation, chunk-level flash softmax ----------
// 4 nodes/block (1 wave each). Lane l: head h=l>>4, chunk-edge slot e4=l&15,
// owns channels c0=4l..4l+3. Per 16-edge chunk: ONE logit+exp per (edge,head)
// computed lane-parallel; chunk max via 4 shfl_xor; one rescale per chunk;
// inner loop redistributes ex/src via shuffles and gathers hp rows (uint2).
__global__ __launch_bounds__(256) void aggregate(const int* __restrict__ rowptr,
                                                 const int* __restrict__ smeta,
                                                 const float* __restrict__ escl,
                                                 const float* __restrict__ s_src,
                                                 const float* __restrict__ s_dst,
                                                 const ushort* __restrict__ hpb,
                                                 const float* __restrict__ h_in,
                                                 float* __restrict__ h_out,
                                                 ushort* __restrict__ h_out_bf,
                                                 int N) {
    int wv = threadIdx.x >> 6;
    int n = blockIdx.x * 4 + wv;
    if (n >= N) return;
    int l = threadIdx.x & 63;
    int h = l >> 4;
    int e4 = l & 15;
    int c0 = l * 4;
    float sdn = s_dst[n * 4 + h];
    int beg = rowptr[n];
    int cnt = rowptr[n + 1] - beg;
    float m = -3e38f, dsum = 0.f, a0 = 0.f, a1 = 0.f, a2 = 0.f, a3 = 0.f;
    for (int ch = 0; ch < cnt; ch += 16) {
        int i = ch + e4;
        int s = 0;
        float lg = -3e38f;
        if (i < cnt) {
            s = smeta[beg + i];
            float tv = sdn + s_src[s * 4 + h] + escl[(size_t)(beg + i) * 4 + h];
            lg = tv > 0.f ? tv : NEG_SLOPE * tv;
        }
        float cm = lg;
#pragma unroll
        for (int off = 1; off < 16; off <<= 1)
            cm = fmaxf(cm, __shfl_xor(cm, off, 64));
        float mn = fmaxf(m, cm);
        float scl = __expf(m - mn);     // 0 on first chunk (m-mn -> -inf)
        m = mn;
        dsum *= scl; a0 *= scl; a1 *= scl; a2 *= scl; a3 *= scl;
        float ex = __expf(lg - mn);     // 0 for invalid lanes
        int lim = min(16, cnt - ch);
#pragma unroll 4
        for (int j = 0; j < lim; ++j) {
            float exj = __shfl(ex, (h << 4) | j, 64);
            int sj = __shfl(s, j, 64);
            uint2 v = *(const uint2*)(hpb + (size_t)sj * HIDDEN + c0);
            dsum += exj;
            float f0 = __uint_as_float(v.x << 16);
            float f1 = __uint_as_float(v.x & 0xFFFF0000u);
            float f2 = __uint_as_float(v.y << 16);
            float f3 = __uint_as_float(v.y & 0xFFFF0000u);
            a0 = fmaf(f0, exj, a0);
            a1 = fmaf(f1, exj, a1);
            a2 = fmaf(f2, exj, a2);
            a3 = fmaf(f3, exj, a3);
        }
    }
    float inv = 1.f / fmaxf(dsum, 1e-16f);
    float4 hi = *(const float4*)(h_in + (size_t)n * HIDDEN + c0);
    float y0 = elu_f(fmaf(a0, inv, hi.x));
    float y1 = elu_f(fmaf(a1, inv, hi.y));
    float y2 = elu_f(fmaf(a2, inv, hi.z));
    float y3 = elu_f(fmaf(a3, inv, hi.w));
    float4 yo = {y0, y1, y2, y3};
    *(float4*)(h_out + (size_t)n * HIDDEN + c0) = yo;
    ushort4 yb = {f2bf(y0), f2bf(y1), f2bf(y2), f2bf(y3)};
    *(ushort4*)(h_out_bf + (size_t)n * HIDDEN + c0) = yb;
}

// ---------- parallel pool ----------
__global__ __launch_bounds__(256) void pool_partial(const float* __restrict__ nemb,
                                                    const int* __restrict__ batch,
                                                    float* __restrict__ gout, int N) {
    int r0 = blockIdx.x * 128;
    int c = threadIdx.x;
    __shared__ int bsh[128];
    if (c < 128) {
        int r = r0 + c;
        bsh[c] = (r < N) ? batch[r] : -1;
    }
    __syncthreads();
    int rend = min(128, N - r0);
    float acc = 0.f;
    int cur = bsh[0];
    for (int i = 0; i < rend; ++i) {
        int g = bsh[i];
        if (g != cur) {
            atomicAdd(&gout[cur * HIDDEN + c], acc);
            acc = 0.f;
            cur = g;
        }
        acc += nemb[(size_t)(r0 + i) * HIDDEN + c];
    }
    if (cur >= 0) atomicAdd(&gout[cur * HIDDEN + c], acc);
}

// divide by per-graph count (count via binary search, fused)
__global__ void pool_div(float* __restrict__ gout, const int* __restrict__ batch, int N) {
    int g = blockIdx.x;
    int c = threadIdx.x;
    int lo = 0, hi = N;
    while (lo < hi) { int mid = (lo + hi) >> 1; if (batch[mid] < g) lo = mid + 1; else hi = mid; }
    int start = lo;
    lo = start; hi = N;
    while (lo < hi) { int mid = (lo + hi) >> 1; if (batch[mid] < g + 1) lo = mid + 1; else hi = mid; }
    float cnt = (float)(lo - start);
    gout[g * HIDDEN + c] /= fmaxf(cnt, 1.f);
}

extern "C" void kernel_launch(void* const* d_in, const int* in_sizes, int n_in,
                              void* d_out, int out_size, void* d_ws, size_t ws_size,
                              hipStream_t stream) {
    const float* x       = (const float*)d_in[0];
    const int*   ei      = (const int*)d_in[1];
    const float* ea      = (const float*)d_in[2];
    const int*   batch   = (const int*)d_in[3];
    const float* W_in    = (const float*)d_in[4];
    const float* b_in    = (const float*)d_in[5];
    const float* ln_in_g = (const float*)d_in[6];
    const float* ln_in_b = (const float*)d_in[7];
    const float* W_gat   = (const float*)d_in[8];
    const float* b_gat   = (const float*)d_in[9];
    const float* W_e     = (const float*)d_in[10];
    const float* a_src   = (const float*)d_in[11];
    const float* a_dst   = (const float*)d_in[12];
    const float* a_edge  = (const float*)d_in[13];
    const float* W_out   = (const float*)d_in[14];
    const float* b_out   = (const float*)d_in[15];
    const float* ln_out_g= (const float*)d_in[16];
    const float* ln_out_b= (const float*)d_in[17];

    int N = in_sizes[0] / 8;
    int E = in_sizes[1] / 2;
    int Mpad = (N + 127) & ~127;
    const int* srcA = ei;
    const int* dstA = ei + E;

    char* w = (char*)d_ws;
    size_t off = 0;
    auto alloc = [&](size_t bytes) {
        void* p = w + off;
        off += (bytes + 255) & ~(size_t)255;
        return p;
    };
    float*    hA     = (float*)alloc((size_t)Mpad * HIDDEN * 4);
    float*    hB     = (float*)alloc((size_t)Mpad * HIDDEN * 4);
    ushort*   hAb    = (ushort*)alloc((size_t)Mpad * HIDDEN * 2);
    ushort*   hBb    = (ushort*)alloc((size_t)Mpad * HIDDEN * 2);
    ushort*   hpb    = (ushort*)alloc((size_t)Mpad * HIDDEN * 2);
    float*    sSrc   = (float*)alloc((size_t)Mpad * 4 * 4);
    float*    sDst   = (float*)alloc((size_t)Mpad * 4 * 4);
    int*      deg    = (int*)alloc((size_t)N * 4);
    int*      rowptr = (int*)alloc((size_t)(N + 1) * 4);
    int*      nxt    = (int*)alloc((size_t)N * 4);
    int*      smeta  = (int*)alloc((size_t)E * 4);
    float*    esc0   = (float*)alloc((size_t)E * 4 * 4);
    float*    esc1   = (float*)alloc((size_t)E * 4 * 4);
    float*    esc2   = (float*)alloc((size_t)E * 4 * 4);
    float*    wea    = (float*)alloc(64 * 4);
    ushort*   Wt     = (ushort*)alloc((size_t)4 * HIDDEN * HIDDEN * 2);
    float*    escs[3] = {esc0, esc1, esc2};

    // --- CSR by dst + per-edge static metadata + weight prep ---
    hipMemsetAsync(deg, 0, (size_t)N * 4, stream);
    hist_kernel<<<(E + 255) / 256, 256, 0, stream>>>(dstA, deg, E);
    scan_kernel<<<1, 256, 0, stream>>>(deg, rowptr, nxt, N, E);
    wea_kernel<<<1, 64, 0, stream>>>(W_e, a_edge, wea);
    scatter_kernel<<<(E + 255) / 256, 256, 0, stream>>>(srcA, dstA, ea, wea, nxt,
                                                        smeta, esc0, esc1, esc2, E);
    conv_w<<<dim3(4, HIDDEN), 256, 0, stream>>>(W_gat, W_out, Wt);

    // --- input projection + LN + ELU ---
    inproj_ln<<<N, 256, 0, stream>>>(x, W_in, b_in, ln_in_g, ln_in_b, hA, hAb);

    float* hcur = hA;   ushort* hcurb = hAb;
    float* hnext = hB;  ushort* hnextb = hBb;
    dim3 gg(Mpad / 128, HIDDEN / 128);
    for (int l = 0; l < LAYERS; ++l) {
        gemm_mfma<<<gg, 256, 0, stream>>>(hcurb, Wt + (size_t)l * HIDDEN * HIDDEN,
                                          b_gat + l * HIDDEN, nullptr, hpb,
                                          a_src + l * HIDDEN, a_dst + l * HIDDEN,
                                          sSrc, sDst, 1);
        aggregate<<<(N + 3) / 4, 256, 0, stream>>>(rowptr, smeta, escs[l], sSrc, sDst,
                                                   hpb, hcur, hnext, hnextb, N);
        float* tf = hcur; hcur = hnext; hnext = tf;
        ushort* tb = hcurb; hcurb = hnextb; hnextb = tb;
    }

    // --- output projection + LN + pool ---
    float* hp32 = hnext;
    gemm_mfma<<<gg, 256, 0, stream>>>(hcurb, Wt + (size_t)3 * HIDDEN * HIDDEN,
                                      b_out, hp32, hpb, a_src, a_dst, sSrc, sDst, 0);
    float* gout = (float*)d_out;
    float* nemb = gout + (size_t)NUM_GRAPHS * HIDDEN;
    ln_elu<<<N, 256, 0, stream>>>(hp32, ln_out_g, ln_out_b, nemb);
    hipMemsetAsync(gout, 0, (size_t)NUM_GRAPHS * HIDDEN * 4, stream);
    pool_partial<<<(N + 127) / 128, 256, 0, stream>>>(nemb, batch, gout, N);
    pool_div<<<NUM_GRAPHS, 256, 0, stream>>>(gout, batch, N);
}

// Round 5
// 749.547 us; speedup vs baseline: 3.2269x; 1.1330x over previous
//
#include <hip/hip_runtime.h>
#include <math.h>

#define HIDDEN 256
#define HEADS 4
#define HEAD_DIM 64
#define LAYERS 3
#define NUM_GRAPHS 64
#define NEG_SLOPE 0.2f

typedef short short8 __attribute__((ext_vector_type(8)));
typedef float floatx4 __attribute__((ext_vector_type(4)));

// ---------- helpers ----------
static __device__ __forceinline__ float elu_f(float x) {
    return x > 0.f ? x : expm1f(x);
}

static __device__ __forceinline__ float waveReduceSum(float v) {
#pragma unroll
    for (int off = 32; off > 0; off >>= 1) v += __shfl_xor(v, off, 64);
    return v;
}

// fp32 <-> bf16 (RNE)
static __device__ __forceinline__ ushort f2bf(float f) {
    unsigned u = __float_as_uint(f);
    unsigned r = (u + 0x7FFFu + ((u >> 16) & 1u)) >> 16;
    return (ushort)r;
}
static __device__ __forceinline__ float bf2f(ushort h) {
    return __uint_as_float(((unsigned)h) << 16);
}

// ---------- CSR build ----------
__global__ void hist_kernel(const int* __restrict__ dst, int* __restrict__ deg, int E) {
    int e = blockIdx.x * blockDim.x + threadIdx.x;
    if (e < E) atomicAdd(&deg[dst[e]], 1);
}

// stage 1: per-block sums of deg (256 elements per block)
__global__ __launch_bounds__(256) void blocksum_kernel(const int* __restrict__ deg,
                                                       int* __restrict__ bsum, int N) {
    int i = blockIdx.x * 256 + threadIdx.x;
    int v = (i < N) ? deg[i] : 0;
    __shared__ int red[4];
    int s = v;
#pragma unroll
    for (int off = 32; off > 0; off >>= 1) s += __shfl_xor(s, off, 64);
    if ((threadIdx.x & 63) == 0) red[threadIdx.x >> 6] = s;
    __syncthreads();
    if (threadIdx.x == 0) bsum[blockIdx.x] = red[0] + red[1] + red[2] + red[3];
}

// stage 2: exclusive scan of <=256 block sums (single block, Hillis-Steele)
__global__ __launch_bounds__(256) void scan_bsums(int* __restrict__ bsum, int nblk) {
    __shared__ int sh[256];
    int t = threadIdx.x;
    int v = (t < nblk) ? bsum[t] : 0;
    sh[t] = v;
    __syncthreads();
#pragma unroll
    for (int off = 1; off < 256; off <<= 1) {
        int add = (t >= off) ? sh[t - off] : 0;
        __syncthreads();
        sh[t] += add;
        __syncthreads();
    }
    if (t < nblk) bsum[t] = sh[t] - v;   // exclusive
}

// stage 3: in-block exclusive scan + block offset -> rowptr, nxt
__global__ __launch_bounds__(256) void writeptr_kernel(const int* __restrict__ deg,
                                                       const int* __restrict__ bsum,
                                                       int* __restrict__ rowptr,
                                                       int* __restrict__ nxt,
                                                       int N, int E) {
    __shared__ int sh[256];
    int t = threadIdx.x;
    int i = blockIdx.x * 256 + t;
    int v = (i < N) ? deg[i] : 0;
    sh[t] = v;
    __syncthreads();
#pragma unroll
    for (int off = 1; off < 256; off <<= 1) {
        int add = (t >= off) ? sh[t - off] : 0;
        __syncthreads();
        sh[t] += add;
        __syncthreads();
    }
    if (i < N) {
        int r = bsum[blockIdx.x] + sh[t] - v;
        rowptr[i] = r;
        nxt[i] = r;
    }
    if (i == 0) rowptr[N] = E;
}

// scatter: CSR-order per-edge metadata. smeta[slot]=src node;
// esc_l[l][slot*4+h] = ea[e,:] . wea[l,h,:]
__global__ void scatter_kernel(const int* __restrict__ src, const int* __restrict__ dst,
                               const float* __restrict__ ea, const float* __restrict__ wea,
                               int* __restrict__ nxt, int* __restrict__ smeta,
                               float* __restrict__ esc0, float* __restrict__ esc1,
                               float* __restrict__ esc2, int E) {
    int e = blockIdx.x * blockDim.x + threadIdx.x;
    if (e >= E) return;
    int d = dst[e];
    int slot = atomicAdd(&nxt[d], 1);
    smeta[slot] = src[e];
    float e0 = ea[(size_t)e * 3], e1 = ea[(size_t)e * 3 + 1], e2 = ea[(size_t)e * 3 + 2];
    float* escs[3] = {esc0, esc1, esc2};
#pragma unroll
    for (int l = 0; l < 3; ++l) {
        float4 v;
        float* vp = (float*)&v;
#pragma unroll
        for (int h = 0; h < 4; ++h) {
            const float* w = wea + l * 12 + h * 3;
            vp[h] = e0 * w[0] + e1 * w[1] + e2 * w[2];
        }
        *(float4*)(escs[l] + (size_t)slot * 4) = v;
    }
}

// ---------- tiny precompute: w_ea[l][h][k] = sum_d We[l,k,h*64+d] * a_e[l,h,d] ----------
__global__ void wea_kernel(const float* __restrict__ We, const float* __restrict__ a_e,
                           float* __restrict__ w_ea) {
    int t = threadIdx.x;
    if (t < LAYERS * HEADS * 3) {
        int l = t / 12, r = t % 12, h = r / 3, k = r % 3;
        float s = 0.f;
        for (int d = 0; d < HEAD_DIM; ++d)
            s += We[l * 3 * HIDDEN + k * HIDDEN + h * HEAD_DIM + d] *
                 a_e[l * HIDDEN + h * HEAD_DIM + d];
        w_ea[t] = s;
    }
}

// ---------- weight convert+transpose: Wt[l][n][k] = bf16(W_l[k][n]) ----------
__global__ void conv_w(const float* __restrict__ Wg, const float* __restrict__ Wo,
                       ushort* __restrict__ Wt) {
    int l = blockIdx.x;
    int n = blockIdx.y;
    int k = threadIdx.x;
    const float* W = (l < 3) ? (Wg + (size_t)l * HIDDEN * HIDDEN) : Wo;
    Wt[(size_t)l * HIDDEN * HIDDEN + (size_t)n * HIDDEN + k] =
        f2bf(W[(size_t)k * HIDDEN + n]);
}

// ---------- input projection + LayerNorm + ELU (fp32 + bf16 outputs) ----------
__global__ __launch_bounds__(256) void inproj_ln(const float* __restrict__ x,
                                                 const float* __restrict__ W,
                                                 const float* __restrict__ b,
                                                 const float* __restrict__ g,
                                                 const float* __restrict__ beta,
                                                 float* __restrict__ h,
                                                 ushort* __restrict__ hb) {
    int n = blockIdx.x;
    int c = threadIdx.x;
    float acc = b[c];
#pragma unroll
    for (int k = 0; k < 8; ++k) acc += x[n * 8 + k] * W[k * HIDDEN + c];
    __shared__ float red[8];
    float s = waveReduceSum(acc);
    float s2 = waveReduceSum(acc * acc);
    int w = c >> 6;
    if ((c & 63) == 0) { red[w] = s; red[4 + w] = s2; }
    __syncthreads();
    float mu = (red[0] + red[1] + red[2] + red[3]) * (1.f / 256.f);
    float ms = (red[4] + red[5] + red[6] + red[7]) * (1.f / 256.f);
    float inv = rsqrtf(ms - mu * mu + 1e-5f);
    float y = elu_f((acc - mu) * inv * g[c] + beta[c]);
    h[(size_t)n * HIDDEN + c] = y;
    hb[(size_t)n * HIDDEN + c] = f2bf(y);
}

// ---------- LayerNorm + ELU (final, fp32 input) ----------
__global__ __launch_bounds__(256) void ln_elu(const float* __restrict__ t,
                                              const float* __restrict__ g,
                                              const float* __restrict__ beta,
                                              float* __restrict__ out) {
    int n = blockIdx.x;
    int c = threadIdx.x;
    float acc = t[(size_t)n * HIDDEN + c];
    __shared__ float red[8];
    float s = waveReduceSum(acc);
    float s2 = waveReduceSum(acc * acc);
    int w = c >> 6;
    if ((c & 63) == 0) { red[w] = s; red[4 + w] = s2; }
    __syncthreads();
    float mu = (red[0] + red[1] + red[2] + red[3]) * (1.f / 256.f);
    float ms = (red[4] + red[5] + red[6] + red[7]) * (1.f / 256.f);
    float inv = rsqrtf(ms - mu * mu + 1e-5f);
    float y = (acc - mu) * inv * g[c] + beta[c];
    out[(size_t)n * HIDDEN + c] = elu_f(y);
}

// ---------- bf16 MFMA GEMM + fused per-node attention scores ----------
#define ASTR 40
__global__ __launch_bounds__(256) void gemm_mfma(const ushort* __restrict__ A,
                                                 const ushort* __restrict__ Bt,
                                                 const float* __restrict__ bias,
                                                 float* __restrict__ C32,
                                                 ushort* __restrict__ C16,
                                                 const float* __restrict__ a_s,
                                                 const float* __restrict__ a_d,
                                                 float* __restrict__ s_src,
                                                 float* __restrict__ s_dst,
                                                 int doScore) {
    const int K = 256;
    __shared__ ushort As[128 * ASTR];
    __shared__ ushort Bs[128 * ASTR];
    int m0 = blockIdx.x * 128;
    int n0 = blockIdx.y * 128;
    int t = threadIdx.x;
    int wave = t >> 6, lane = t & 63;
    int wr = wave >> 1, wc = wave & 1;
    int lrow = lane & 15;
    int quad = lane >> 4;
    floatx4 acc[4][4] = {};
    int r = t >> 2, q = t & 3;
    for (int k0 = 0; k0 < K; k0 += 32) {
        __syncthreads();
        *(uint4*)&As[(r) * ASTR + q * 8] =
            *(const uint4*)(A + (size_t)(m0 + r) * K + k0 + q * 8);
        *(uint4*)&As[(r + 64) * ASTR + q * 8] =
            *(const uint4*)(A + (size_t)(m0 + r + 64) * K + k0 + q * 8);
        *(uint4*)&Bs[(r) * ASTR + q * 8] =
            *(const uint4*)(Bt + (size_t)(n0 + r) * K + k0 + q * 8);
        *(uint4*)&Bs[(r + 64) * ASTR + q * 8] =
            *(const uint4*)(Bt + (size_t)(n0 + r + 64) * K + k0 + q * 8);
        __syncthreads();
        short8 af[4], bfr[4];
#pragma unroll
        for (int i = 0; i < 4; ++i)
            af[i] = *(const short8*)&As[(wr * 64 + i * 16 + lrow) * ASTR + quad * 8];
#pragma unroll
        for (int j = 0; j < 4; ++j)
            bfr[j] = *(const short8*)&Bs[(wc * 64 + j * 16 + lrow) * ASTR + quad * 8];
#pragma unroll
        for (int i = 0; i < 4; ++i)
#pragma unroll
            for (int j = 0; j < 4; ++j)
                acc[i][j] = __builtin_amdgcn_mfma_f32_16x16x32_bf16(af[i], bfr[j],
                                                                    acc[i][j], 0, 0, 0);
    }
    int hh = (n0 + wc * 64) >> 6;
    int ncol[4];
    float bv4[4], asv[4], adv[4];
#pragma unroll
    for (int j = 0; j < 4; ++j) {
        int n = n0 + wc * 64 + j * 16 + lrow;
        ncol[j] = n;
        bv4[j] = bias[n];
        asv[j] = a_s[n];
        adv[j] = a_d[n];
    }
#pragma unroll
    for (int i = 0; i < 4; ++i) {
#pragma unroll
        for (int rg = 0; rg < 4; ++rg) {
            int mrow = m0 + wr * 64 + i * 16 + quad * 4 + rg;
            float ps = 0.f, pd = 0.f;
#pragma unroll
            for (int j = 0; j < 4; ++j) {
                float v = acc[i][j][rg] + bv4[j];
                if (C32) C32[(size_t)mrow * HIDDEN + ncol[j]] = v;
                if (C16) C16[(size_t)mrow * HIDDEN + ncol[j]] = f2bf(v);
                ps = fmaf(v, asv[j], ps);
                pd = fmaf(v, adv[j], pd);
            }
            if (doScore) {
#pragma unroll
                for (int off = 1; off < 16; off <<= 1) {
                    ps += __shfl_xor(ps, off, 64);
                    pd += __shfl_xor(pd, off, 64);
                }
                if (lrow == 0) {
                    s_src[mrow * 4 + hh] = ps;
                    s_dst[mrow * 4 + hh] = pd;
                }
            }
        }
    }
}

// ---------- wave-per-node aggregation, chunk-level flash softmax ----------
__global__ __launch_bounds__(256) void aggregate(const int* __restrict__ rowptr,
                                                 const int* __restrict__ smeta,
                                                 const float* __restrict__ escl,
                                                 const float* __restrict__ s_src,
                                                 const float* __restrict__ s_dst,
                                                 const ushort* __restrict__ hpb,
                                                 const float* __restrict__ h_in,
                                                 float* __restrict__ h_out,
                                                 ushort* __restrict__ h_out_bf,
                                                 int N) {
    int wv = threadIdx.x >> 6;
    int n = blockIdx.x * 4 + wv;
    if (n >= N) return;
    int l = threadIdx.x & 63;
    int h = l >> 4;
    int e4 = l & 15;
    int c0 = l * 4;
    float sdn = s_dst[n * 4 + h];
    int beg = rowptr[n];
    int cnt = rowptr[n + 1] - beg;
    float m = -3e38f, dsum = 0.f, a0 = 0.f, a1 = 0.f, a2 = 0.f, a3 = 0.f;
    for (int ch = 0; ch < cnt; ch += 16) {
        int i = ch + e4;
        int s = 0;
        float lg = -3e38f;
        if (i < cnt) {
            s = smeta[beg + i];
            float tv = sdn + s_src[s * 4 + h] + escl[(size_t)(beg + i) * 4 + h];
            lg = tv > 0.f ? tv : NEG_SLOPE * tv;
        }
        float cm = lg;
#pragma unroll
        for (int off = 1; off < 16; off <<= 1)
            cm = fmaxf(cm, __shfl_xor(cm, off, 64));
        float mn = fmaxf(m, cm);
        float scl = __expf(m - mn);
        m = mn;
        dsum *= scl; a0 *= scl; a1 *= scl; a2 *= scl; a3 *= scl;
        float ex = __expf(lg - mn);
        int lim = min(16, cnt - ch);
#pragma unroll 4
        for (int j = 0; j < lim; ++j) {
            float exj = __shfl(ex, (h << 4) | j, 64);
            int sj = __shfl(s, j, 64);
            uint2 v = *(const uint2*)(hpb + (size_t)sj * HIDDEN + c0);
            dsum += exj;
            float f0 = __uint_as_float(v.x << 16);
            float f1 = __uint_as_float(v.x & 0xFFFF0000u);
            float f2 = __uint_as_float(v.y << 16);
            float f3 = __uint_as_float(v.y & 0xFFFF0000u);
            a0 = fmaf(f0, exj, a0);
            a1 = fmaf(f1, exj, a1);
            a2 = fmaf(f2, exj, a2);
            a3 = fmaf(f3, exj, a3);
        }
    }
    float inv = 1.f / fmaxf(dsum, 1e-16f);
    float4 hi = *(const float4*)(h_in + (size_t)n * HIDDEN + c0);
    float y0 = elu_f(fmaf(a0, inv, hi.x));
    float y1 = elu_f(fmaf(a1, inv, hi.y));
    float y2 = elu_f(fmaf(a2, inv, hi.z));
    float y3 = elu_f(fmaf(a3, inv, hi.w));
    float4 yo = {y0, y1, y2, y3};
    *(float4*)(h_out + (size_t)n * HIDDEN + c0) = yo;
    ushort4 yb = {f2bf(y0), f2bf(y1), f2bf(y2), f2bf(y3)};
    *(ushort4*)(h_out_bf + (size_t)n * HIDDEN + c0) = yb;
}

// ---------- parallel pool ----------
__global__ __launch_bounds__(256) void pool_partial(const float* __restrict__ nemb,
                                                    const int* __restrict__ batch,
                                                    float* __restrict__ gout, int N) {
    int r0 = blockIdx.x * 128;
    int c = threadIdx.x;
    __shared__ int bsh[128];
    if (c < 128) {
        int r = r0 + c;
        bsh[c] = (r < N) ? batch[r] : -1;
    }
    __syncthreads();
    int rend = min(128, N - r0);
    float acc = 0.f;
    int cur = bsh[0];
    for (int i = 0; i < rend; ++i) {
        int g = bsh[i];
        if (g != cur) {
            atomicAdd(&gout[cur * HIDDEN + c], acc);
            acc = 0.f;
            cur = g;
        }
        acc += nemb[(size_t)(r0 + i) * HIDDEN + c];
    }
    if (cur >= 0) atomicAdd(&gout[cur * HIDDEN + c], acc);
}

// divide by per-graph count (count via binary search, fused)
__global__ void pool_div(float* __restrict__ gout, const int* __restrict__ batch, int N) {
    int g = blockIdx.x;
    int c = threadIdx.x;
    int lo = 0, hi = N;
    while (lo < hi) { int mid = (lo + hi) >> 1; if (batch[mid] < g) lo = mid + 1; else hi = mid; }
    int start = lo;
    lo = start; hi = N;
    while (lo < hi) { int mid = (lo + hi) >> 1; if (batch[mid] < g + 1) lo = mid + 1; else hi = mid; }
    float cnt = (float)(lo - start);
    gout[g * HIDDEN + c] /= fmaxf(cnt, 1.f);
}

extern "C" void kernel_launch(void* const* d_in, const int* in_sizes, int n_in,
                              void* d_out, int out_size, void* d_ws, size_t ws_size,
                              hipStream_t stream) {
    const float* x       = (const float*)d_in[0];
    const int*   ei      = (const int*)d_in[1];
    const float* ea      = (const float*)d_in[2];
    const int*   batch   = (const int*)d_in[3];
    const float* W_in    = (const float*)d_in[4];
    const float* b_in    = (const float*)d_in[5];
    const float* ln_in_g = (const float*)d_in[6];
    const float* ln_in_b = (const float*)d_in[7];
    const float* W_gat   = (const float*)d_in[8];
    const float* b_gat   = (const float*)d_in[9];
    const float* W_e     = (const float*)d_in[10];
    const float* a_src   = (const float*)d_in[11];
    const float* a_dst   = (const float*)d_in[12];
    const float* a_edge  = (const float*)d_in[13];
    const float* W_out   = (const float*)d_in[14];
    const float* b_out   = (const float*)d_in[15];
    const float* ln_out_g= (const float*)d_in[16];
    const float* ln_out_b= (const float*)d_in[17];

    int N = in_sizes[0] / 8;
    int E = in_sizes[1] / 2;
    int Mpad = (N + 127) & ~127;
    int nblk = (N + 255) / 256;     // <=256 assumed (N<=65536)
    const int* srcA = ei;
    const int* dstA = ei + E;

    char* w = (char*)d_ws;
    size_t off = 0;
    auto alloc = [&](size_t bytes) {
        void* p = w + off;
        off += (bytes + 255) & ~(size_t)255;
        return p;
    };
    float*    hA     = (float*)alloc((size_t)Mpad * HIDDEN * 4);
    float*    hB     = (float*)alloc((size_t)Mpad * HIDDEN * 4);
    ushort*   hAb    = (ushort*)alloc((size_t)Mpad * HIDDEN * 2);
    ushort*   hBb    = (ushort*)alloc((size_t)Mpad * HIDDEN * 2);
    ushort*   hpb    = (ushort*)alloc((size_t)Mpad * HIDDEN * 2);
    float*    sSrc   = (float*)alloc((size_t)Mpad * 4 * 4);
    float*    sDst   = (float*)alloc((size_t)Mpad * 4 * 4);
    int*      deg    = (int*)alloc((size_t)N * 4);
    int*      rowptr = (int*)alloc((size_t)(N + 1) * 4);
    int*      nxt    = (int*)alloc((size_t)N * 4);
    int*      bsum   = (int*)alloc(256 * 4);
    int*      smeta  = (int*)alloc((size_t)E * 4);
    float*    esc0   = (float*)alloc((size_t)E * 4 * 4);
    float*    esc1   = (float*)alloc((size_t)E * 4 * 4);
    float*    esc2   = (float*)alloc((size_t)E * 4 * 4);
    float*    wea    = (float*)alloc(64 * 4);
    ushort*   Wt     = (ushort*)alloc((size_t)4 * HIDDEN * HIDDEN * 2);
    float*    escs[3] = {esc0, esc1, esc2};

    // --- CSR by dst (parallel 3-stage scan) + per-edge metadata + weight prep ---
    hipMemsetAsync(deg, 0, (size_t)N * 4, stream);
    hist_kernel<<<(E + 255) / 256, 256, 0, stream>>>(dstA, deg, E);
    blocksum_kernel<<<nblk, 256, 0, stream>>>(deg, bsum, N);
    scan_bsums<<<1, 256, 0, stream>>>(bsum, nblk);
    writeptr_kernel<<<nblk, 256, 0, stream>>>(deg, bsum, rowptr, nxt, N, E);
    wea_kernel<<<1, 64, 0, stream>>>(W_e, a_edge, wea);
    scatter_kernel<<<(E + 255) / 256, 256, 0, stream>>>(srcA, dstA, ea, wea, nxt,
                                                        smeta, esc0, esc1, esc2, E);
    conv_w<<<dim3(4, HIDDEN), 256, 0, stream>>>(W_gat, W_out, Wt);

    // --- input projection + LN + ELU ---
    inproj_ln<<<N, 256, 0, stream>>>(x, W_in, b_in, ln_in_g, ln_in_b, hA, hAb);

    float* hcur = hA;   ushort* hcurb = hAb;
    float* hnext = hB;  ushort* hnextb = hBb;
    dim3 gg(Mpad / 128, HIDDEN / 128);
    for (int l = 0; l < LAYERS; ++l) {
        gemm_mfma<<<gg, 256, 0, stream>>>(hcurb, Wt + (size_t)l * HIDDEN * HIDDEN,
                                          b_gat + l * HIDDEN, nullptr, hpb,
                                          a_src + l * HIDDEN, a_dst + l * HIDDEN,
                                          sSrc, sDst, 1);
        aggregate<<<(N + 3) / 4, 256, 0, stream>>>(rowptr, smeta, escs[l], sSrc, sDst,
                                                   hpb, hcur, hnext, hnextb, N);
        float* tf = hcur; hcur = hnext; hnext = tf;
        ushort* tb = hcurb; hcurb = hnextb; hnextb = tb;
    }

    // --- output projection + LN + pool (no bf16 C-write needed) ---
    float* hp32 = hnext;
    gemm_mfma<<<gg, 256, 0, stream>>>(hcurb, Wt + (size_t)3 * HIDDEN * HIDDEN,
                                      b_out, hp32, nullptr, a_src, a_dst, sSrc, sDst, 0);
    float* gout = (float*)d_out;
    float* nemb = gout + (size_t)NUM_GRAPHS * HIDDEN;
    ln_elu<<<N, 256, 0, stream>>>(hp32, ln_out_g, ln_out_b, nemb);
    hipMemsetAsync(gout, 0, (size_t)NUM_GRAPHS * HIDDEN * 4, stream);
    pool_partial<<<(N + 127) / 128, 256, 0, stream>>>(nemb, batch, gout, N);
    pool_div<<<NUM_GRAPHS, 256, 0, stream>>>(gout, batch, N);
}

// Round 6
// 687.988 us; speedup vs baseline: 3.5156x; 1.0895x over previous
//
#include <hip/hip_runtime.h>
#include <math.h>

#define HIDDEN 256
#define HEADS 4
#define HEAD_DIM 64
#define LAYERS 3
#define NUM_GRAPHS 64
#define NEG_SLOPE 0.2f

typedef short short8 __attribute__((ext_vector_type(8)));
typedef float floatx4 __attribute__((ext_vector_type(4)));

// ---------- helpers ----------
static __device__ __forceinline__ float elu_f(float x) {
    return x > 0.f ? x : expm1f(x);
}

static __device__ __forceinline__ float waveReduceSum(float v) {
#pragma unroll
    for (int off = 32; off > 0; off >>= 1) v += __shfl_xor(v, off, 64);
    return v;
}

// fp32 <-> bf16 (RNE)
static __device__ __forceinline__ ushort f2bf(float f) {
    unsigned u = __float_as_uint(f);
    unsigned r = (u + 0x7FFFu + ((u >> 16) & 1u)) >> 16;
    return (ushort)r;
}
static __device__ __forceinline__ float bf2f(ushort h) {
    return __uint_as_float(((unsigned)h) << 16);
}

// ---------- CSR build ----------
__global__ void hist_kernel(const int* __restrict__ dst, int* __restrict__ deg, int E) {
    int e = blockIdx.x * blockDim.x + threadIdx.x;
    if (e < E) atomicAdd(&deg[dst[e]], 1);
}

__global__ __launch_bounds__(256) void blocksum_kernel(const int* __restrict__ deg,
                                                       int* __restrict__ bsum, int N) {
    int i = blockIdx.x * 256 + threadIdx.x;
    int v = (i < N) ? deg[i] : 0;
    __shared__ int red[4];
    int s = v;
#pragma unroll
    for (int off = 32; off > 0; off >>= 1) s += __shfl_xor(s, off, 64);
    if ((threadIdx.x & 63) == 0) red[threadIdx.x >> 6] = s;
    __syncthreads();
    if (threadIdx.x == 0) bsum[blockIdx.x] = red[0] + red[1] + red[2] + red[3];
}

__global__ __launch_bounds__(256) void scan_bsums(int* __restrict__ bsum, int nblk) {
    __shared__ int sh[256];
    int t = threadIdx.x;
    int v = (t < nblk) ? bsum[t] : 0;
    sh[t] = v;
    __syncthreads();
#pragma unroll
    for (int off = 1; off < 256; off <<= 1) {
        int add = (t >= off) ? sh[t - off] : 0;
        __syncthreads();
        sh[t] += add;
        __syncthreads();
    }
    if (t < nblk) bsum[t] = sh[t] - v;   // exclusive
}

__global__ __launch_bounds__(256) void writeptr_kernel(const int* __restrict__ deg,
                                                       const int* __restrict__ bsum,
                                                       int* __restrict__ rowptr,
                                                       int* __restrict__ nxt,
                                                       int N, int E) {
    __shared__ int sh[256];
    int t = threadIdx.x;
    int i = blockIdx.x * 256 + t;
    int v = (i < N) ? deg[i] : 0;
    sh[t] = v;
    __syncthreads();
#pragma unroll
    for (int off = 1; off < 256; off <<= 1) {
        int add = (t >= off) ? sh[t - off] : 0;
        __syncthreads();
        sh[t] += add;
        __syncthreads();
    }
    if (i < N) {
        int r = bsum[blockIdx.x] + sh[t] - v;
        rowptr[i] = r;
        nxt[i] = r;
    }
    if (i == 0) rowptr[N] = E;
}

// scatter: ONE packed 16B record per edge in CSR slot order:
// emeta[slot] = { src(int), e0, e1, e2 }
__global__ void scatter_kernel(const int* __restrict__ src, const int* __restrict__ dst,
                               const float* __restrict__ ea,
                               int* __restrict__ nxt, uint4* __restrict__ emeta, int E) {
    int e = blockIdx.x * blockDim.x + threadIdx.x;
    if (e >= E) return;
    int d = dst[e];
    int slot = atomicAdd(&nxt[d], 1);
    uint4 mt;
    mt.x = (unsigned)src[e];
    mt.y = __float_as_uint(ea[(size_t)e * 3]);
    mt.z = __float_as_uint(ea[(size_t)e * 3 + 1]);
    mt.w = __float_as_uint(ea[(size_t)e * 3 + 2]);
    emeta[slot] = mt;
}

// ---------- tiny precompute: w_ea[l][h][k] = sum_d We[l,k,h*64+d] * a_e[l,h,d] ----------
__global__ void wea_kernel(const float* __restrict__ We, const float* __restrict__ a_e,
                           float* __restrict__ w_ea) {
    int t = threadIdx.x;
    if (t < LAYERS * HEADS * 3) {
        int l = t / 12, r = t % 12, h = r / 3, k = r % 3;
        float s = 0.f;
        for (int d = 0; d < HEAD_DIM; ++d)
            s += We[l * 3 * HIDDEN + k * HIDDEN + h * HEAD_DIM + d] *
                 a_e[l * HIDDEN + h * HEAD_DIM + d];
        w_ea[t] = s;
    }
}

// ---------- weight convert+transpose: Wt[l][n][k] = bf16(W_l[k][n]) ----------
__global__ void conv_w(const float* __restrict__ Wg, const float* __restrict__ Wo,
                       ushort* __restrict__ Wt) {
    int l = blockIdx.x;
    int n = blockIdx.y;
    int k = threadIdx.x;
    const float* W = (l < 3) ? (Wg + (size_t)l * HIDDEN * HIDDEN) : Wo;
    Wt[(size_t)l * HIDDEN * HIDDEN + (size_t)n * HIDDEN + k] =
        f2bf(W[(size_t)k * HIDDEN + n]);
}

// ---------- input projection + LayerNorm + ELU (fp32 + bf16 outputs) ----------
__global__ __launch_bounds__(256) void inproj_ln(const float* __restrict__ x,
                                                 const float* __restrict__ W,
                                                 const float* __restrict__ b,
                                                 const float* __restrict__ g,
                                                 const float* __restrict__ beta,
                                                 float* __restrict__ h,
                                                 ushort* __restrict__ hb) {
    int n = blockIdx.x;
    int c = threadIdx.x;
    float acc = b[c];
#pragma unroll
    for (int k = 0; k < 8; ++k) acc += x[n * 8 + k] * W[k * HIDDEN + c];
    __shared__ float red[8];
    float s = waveReduceSum(acc);
    float s2 = waveReduceSum(acc * acc);
    int w = c >> 6;
    if ((c & 63) == 0) { red[w] = s; red[4 + w] = s2; }
    __syncthreads();
    float mu = (red[0] + red[1] + red[2] + red[3]) * (1.f / 256.f);
    float ms = (red[4] + red[5] + red[6] + red[7]) * (1.f / 256.f);
    float inv = rsqrtf(ms - mu * mu + 1e-5f);
    float y = elu_f((acc - mu) * inv * g[c] + beta[c]);
    h[(size_t)n * HIDDEN + c] = y;
    hb[(size_t)n * HIDDEN + c] = f2bf(y);
}

// ---------- LayerNorm + ELU (final, fp32 input) ----------
__global__ __launch_bounds__(256) void ln_elu(const float* __restrict__ t,
                                              const float* __restrict__ g,
                                              const float* __restrict__ beta,
                                              float* __restrict__ out) {
    int n = blockIdx.x;
    int c = threadIdx.x;
    float acc = t[(size_t)n * HIDDEN + c];
    __shared__ float red[8];
    float s = waveReduceSum(acc);
    float s2 = waveReduceSum(acc * acc);
    int w = c >> 6;
    if ((c & 63) == 0) { red[w] = s; red[4 + w] = s2; }
    __syncthreads();
    float mu = (red[0] + red[1] + red[2] + red[3]) * (1.f / 256.f);
    float ms = (red[4] + red[5] + red[6] + red[7]) * (1.f / 256.f);
    float inv = rsqrtf(ms - mu * mu + 1e-5f);
    float y = (acc - mu) * inv * g[c] + beta[c];
    out[(size_t)n * HIDDEN + c] = elu_f(y);
}

// ---------- bf16 MFMA GEMM (register double-buffered) + fused scores ----------
#define ASTR 40
__global__ __launch_bounds__(256) void gemm_mfma(const ushort* __restrict__ A,
                                                 const ushort* __restrict__ Bt,
                                                 const float* __restrict__ bias,
                                                 float* __restrict__ C32,
                                                 ushort* __restrict__ C16,
                                                 const float* __restrict__ a_s,
                                                 const float* __restrict__ a_d,
                                                 float* __restrict__ s_src,
                                                 float* __restrict__ s_dst,
                                                 int doScore) {
    const int K = 256;
    __shared__ ushort As[128 * ASTR];
    __shared__ ushort Bs[128 * ASTR];
    int m0 = blockIdx.x * 128;
    int n0 = blockIdx.y * 128;
    int t = threadIdx.x;
    int wave = t >> 6, lane = t & 63;
    int wr = wave >> 1, wc = wave & 1;
    int lrow = lane & 15;
    int quad = lane >> 4;
    floatx4 acc[4][4] = {};
    int r = t >> 2, q = t & 3;
    const ushort* Ar0 = A + (size_t)(m0 + r) * K + q * 8;
    const ushort* Ar1 = A + (size_t)(m0 + r + 64) * K + q * 8;
    const ushort* Br0 = Bt + (size_t)(n0 + r) * K + q * 8;
    const ushort* Br1 = Bt + (size_t)(n0 + r + 64) * K + q * 8;
    uint4 ra0 = *(const uint4*)(Ar0);
    uint4 ra1 = *(const uint4*)(Ar1);
    uint4 rb0 = *(const uint4*)(Br0);
    uint4 rb1 = *(const uint4*)(Br1);
    for (int k0 = 0; k0 < K; k0 += 32) {
        *(uint4*)&As[(r) * ASTR + q * 8] = ra0;
        *(uint4*)&As[(r + 64) * ASTR + q * 8] = ra1;
        *(uint4*)&Bs[(r) * ASTR + q * 8] = rb0;
        *(uint4*)&Bs[(r + 64) * ASTR + q * 8] = rb1;
        __syncthreads();
        if (k0 + 32 < K) {   // prefetch next tile while MFMA runs on this one
            ra0 = *(const uint4*)(Ar0 + k0 + 32);
            ra1 = *(const uint4*)(Ar1 + k0 + 32);
            rb0 = *(const uint4*)(Br0 + k0 + 32);
            rb1 = *(const uint4*)(Br1 + k0 + 32);
        }
        short8 af[4], bfr[4];
#pragma unroll
        for (int i = 0; i < 4; ++i)
            af[i] = *(const short8*)&As[(wr * 64 + i * 16 + lrow) * ASTR + quad * 8];
#pragma unroll
        for (int j = 0; j < 4; ++j)
            bfr[j] = *(const short8*)&Bs[(wc * 64 + j * 16 + lrow) * ASTR + quad * 8];
#pragma unroll
        for (int i = 0; i < 4; ++i)
#pragma unroll
            for (int j = 0; j < 4; ++j)
                acc[i][j] = __builtin_amdgcn_mfma_f32_16x16x32_bf16(af[i], bfr[j],
                                                                    acc[i][j], 0, 0, 0);
        __syncthreads();
    }
    int hh = (n0 + wc * 64) >> 6;
    int ncol[4];
    float bv4[4], asv[4], adv[4];
#pragma unroll
    for (int j = 0; j < 4; ++j) {
        int n = n0 + wc * 64 + j * 16 + lrow;
        ncol[j] = n;
        bv4[j] = bias[n];
        asv[j] = a_s[n];
        adv[j] = a_d[n];
    }
#pragma unroll
    for (int i = 0; i < 4; ++i) {
#pragma unroll
        for (int rg = 0; rg < 4; ++rg) {
            int mrow = m0 + wr * 64 + i * 16 + quad * 4 + rg;
            float ps = 0.f, pd = 0.f;
#pragma unroll
            for (int j = 0; j < 4; ++j) {
                float v = acc[i][j][rg] + bv4[j];
                if (C32) C32[(size_t)mrow * HIDDEN + ncol[j]] = v;
                if (C16) C16[(size_t)mrow * HIDDEN + ncol[j]] = f2bf(v);
                ps = fmaf(v, asv[j], ps);
                pd = fmaf(v, adv[j], pd);
            }
            if (doScore) {
#pragma unroll
                for (int off = 1; off < 16; off <<= 1) {
                    ps += __shfl_xor(ps, off, 64);
                    pd += __shfl_xor(pd, off, 64);
                }
                if (lrow == 0) {
                    s_src[mrow * 4 + hh] = ps;
                    s_dst[mrow * 4 + hh] = pd;
                }
            }
        }
    }
}

// ---------- wave-per-node aggregation, chunk-level flash softmax ----------
// 4 nodes/block. Lane l: head h=l>>4, chunk slot e4=l&15, channels c0=4l..4l+3.
// Per-edge metadata is one 16B record {src,e0,e1,e2}; esc = ea.wea computed
// on the fly (3 FMA) instead of precomputed arrays.
__global__ __launch_bounds__(256) void aggregate(const int* __restrict__ rowptr,
                                                 const uint4* __restrict__ emeta,
                                                 const float* __restrict__ wea_l,
                                                 const float* __restrict__ s_src,
                                                 const float* __restrict__ s_dst,
                                                 const ushort* __restrict__ hpb,
                                                 const float* __restrict__ h_in,
                                                 float* __restrict__ h_out,
                                                 ushort* __restrict__ h_out_bf,
                                                 int N) {
    int wv = threadIdx.x >> 6;
    int n = blockIdx.x * 4 + wv;
    if (n >= N) return;
    int l = threadIdx.x & 63;
    int h = l >> 4;
    int e4 = l & 15;
    int c0 = l * 4;
    float w0 = wea_l[h * 3], w1 = wea_l[h * 3 + 1], w2 = wea_l[h * 3 + 2];
    float sdn = s_dst[n * 4 + h];
    int beg = rowptr[n];
    int cnt = rowptr[n + 1] - beg;
    float m = -3e38f, dsum = 0.f, a0 = 0.f, a1 = 0.f, a2 = 0.f, a3 = 0.f;
    for (int ch = 0; ch < cnt; ch += 16) {
        int i = ch + e4;
        int s = 0;
        float lg = -3e38f;
        if (i < cnt) {
            uint4 mt = emeta[beg + i];
            s = (int)mt.x;
            float esc = __uint_as_float(mt.y) * w0 + __uint_as_float(mt.z) * w1 +
                        __uint_as_float(mt.w) * w2;
            float tv = sdn + s_src[s * 4 + h] + esc;
            lg = tv > 0.f ? tv : NEG_SLOPE * tv;
        }
        float cm = lg;
#pragma unroll
        for (int off = 1; off < 16; off <<= 1)
            cm = fmaxf(cm, __shfl_xor(cm, off, 64));
        float mn = fmaxf(m, cm);
        float scl = __expf(m - mn);
        m = mn;
        dsum *= scl; a0 *= scl; a1 *= scl; a2 *= scl; a3 *= scl;
        float ex = __expf(lg - mn);
        int lim = min(16, cnt - ch);
#pragma unroll 4
        for (int j = 0; j < lim; ++j) {
            float exj = __shfl(ex, (h << 4) | j, 64);
            int sj = __shfl(s, j, 64);
            uint2 v = *(const uint2*)(hpb + (size_t)sj * HIDDEN + c0);
            dsum += exj;
            float f0 = __uint_as_float(v.x << 16);
            float f1 = __uint_as_float(v.x & 0xFFFF0000u);
            float f2 = __uint_as_float(v.y << 16);
            float f3 = __uint_as_float(v.y & 0xFFFF0000u);
            a0 = fmaf(f0, exj, a0);
            a1 = fmaf(f1, exj, a1);
            a2 = fmaf(f2, exj, a2);
            a3 = fmaf(f3, exj, a3);
        }
    }
    float inv = 1.f / fmaxf(dsum, 1e-16f);
    float4 hi = *(const float4*)(h_in + (size_t)n * HIDDEN + c0);
    float y0 = elu_f(fmaf(a0, inv, hi.x));
    float y1 = elu_f(fmaf(a1, inv, hi.y));
    float y2 = elu_f(fmaf(a2, inv, hi.z));
    float y3 = elu_f(fmaf(a3, inv, hi.w));
    float4 yo = {y0, y1, y2, y3};
    *(float4*)(h_out + (size_t)n * HIDDEN + c0) = yo;
    ushort4 yb = {f2bf(y0), f2bf(y1), f2bf(y2), f2bf(y3)};
    *(ushort4*)(h_out_bf + (size_t)n * HIDDEN + c0) = yb;
}

// ---------- parallel pool ----------
__global__ __launch_bounds__(256) void pool_partial(const float* __restrict__ nemb,
                                                    const int* __restrict__ batch,
                                                    float* __restrict__ gout, int N) {
    int r0 = blockIdx.x * 128;
    int c = threadIdx.x;
    __shared__ int bsh[128];
    if (c < 128) {
        int r = r0 + c;
        bsh[c] = (r < N) ? batch[r] : -1;
    }
    __syncthreads();
    int rend = min(128, N - r0);
    float acc = 0.f;
    int cur = bsh[0];
    for (int i = 0; i < rend; ++i) {
        int g = bsh[i];
        if (g != cur) {
            atomicAdd(&gout[cur * HIDDEN + c], acc);
            acc = 0.f;
            cur = g;
        }
        acc += nemb[(size_t)(r0 + i) * HIDDEN + c];
    }
    if (cur >= 0) atomicAdd(&gout[cur * HIDDEN + c], acc);
}

__global__ void pool_div(float* __restrict__ gout, const int* __restrict__ batch, int N) {
    int g = blockIdx.x;
    int c = threadIdx.x;
    int lo = 0, hi = N;
    while (lo < hi) { int mid = (lo + hi) >> 1; if (batch[mid] < g) lo = mid + 1; else hi = mid; }
    int start = lo;
    lo = start; hi = N;
    while (lo < hi) { int mid = (lo + hi) >> 1; if (batch[mid] < g + 1) lo = mid + 1; else hi = mid; }
    float cnt = (float)(lo - start);
    gout[g * HIDDEN + c] /= fmaxf(cnt, 1.f);
}

extern "C" void kernel_launch(void* const* d_in, const int* in_sizes, int n_in,
                              void* d_out, int out_size, void* d_ws, size_t ws_size,
                              hipStream_t stream) {
    const float* x       = (const float*)d_in[0];
    const int*   ei      = (const int*)d_in[1];
    const float* ea      = (const float*)d_in[2];
    const int*   batch   = (const int*)d_in[3];
    const float* W_in    = (const float*)d_in[4];
    const float* b_in    = (const float*)d_in[5];
    const float* ln_in_g = (const float*)d_in[6];
    const float* ln_in_b = (const float*)d_in[7];
    const float* W_gat   = (const float*)d_in[8];
    const float* b_gat   = (const float*)d_in[9];
    const float* W_e     = (const float*)d_in[10];
    const float* a_src   = (const float*)d_in[11];
    const float* a_dst   = (const float*)d_in[12];
    const float* a_edge  = (const float*)d_in[13];
    const float* W_out   = (const float*)d_in[14];
    const float* b_out   = (const float*)d_in[15];
    const float* ln_out_g= (const float*)d_in[16];
    const float* ln_out_b= (const float*)d_in[17];

    int N = in_sizes[0] / 8;
    int E = in_sizes[1] / 2;
    int Mpad = (N + 127) & ~127;
    int nblk = (N + 255) / 256;     // <=256 assumed (N<=65536)
    const int* srcA = ei;
    const int* dstA = ei + E;

    char* w = (char*)d_ws;
    size_t off = 0;
    auto alloc = [&](size_t bytes) {
        void* p = w + off;
        off += (bytes + 255) & ~(size_t)255;
        return p;
    };
    float*    hA     = (float*)alloc((size_t)Mpad * HIDDEN * 4);
    float*    hB     = (float*)alloc((size_t)Mpad * HIDDEN * 4);
    ushort*   hAb    = (ushort*)alloc((size_t)Mpad * HIDDEN * 2);
    ushort*   hBb    = (ushort*)alloc((size_t)Mpad * HIDDEN * 2);
    ushort*   hpb    = (ushort*)alloc((size_t)Mpad * HIDDEN * 2);
    float*    sSrc   = (float*)alloc((size_t)Mpad * 4 * 4);
    float*    sDst   = (float*)alloc((size_t)Mpad * 4 * 4);
    int*      deg    = (int*)alloc((size_t)N * 4);
    int*      rowptr = (int*)alloc((size_t)(N + 1) * 4);
    int*      nxt    = (int*)alloc((size_t)N * 4);
    int*      bsum   = (int*)alloc(256 * 4);
    uint4*    emeta  = (uint4*)alloc((size_t)E * 16);
    float*    wea    = (float*)alloc(64 * 4);
    ushort*   Wt     = (ushort*)alloc((size_t)4 * HIDDEN * HIDDEN * 2);

    // --- CSR by dst (parallel 3-stage scan) + packed edge metadata + weights ---
    hipMemsetAsync(deg, 0, (size_t)N * 4, stream);
    hist_kernel<<<(E + 255) / 256, 256, 0, stream>>>(dstA, deg, E);
    blocksum_kernel<<<nblk, 256, 0, stream>>>(deg, bsum, N);
    scan_bsums<<<1, 256, 0, stream>>>(bsum, nblk);
    writeptr_kernel<<<nblk, 256, 0, stream>>>(deg, bsum, rowptr, nxt, N, E);
    wea_kernel<<<1, 64, 0, stream>>>(W_e, a_edge, wea);
    scatter_kernel<<<(E + 255) / 256, 256, 0, stream>>>(srcA, dstA, ea, nxt, emeta, E);
    conv_w<<<dim3(4, HIDDEN), 256, 0, stream>>>(W_gat, W_out, Wt);

    // --- input projection + LN + ELU ---
    inproj_ln<<<N, 256, 0, stream>>>(x, W_in, b_in, ln_in_g, ln_in_b, hA, hAb);

    float* hcur = hA;   ushort* hcurb = hAb;
    float* hnext = hB;  ushort* hnextb = hBb;
    dim3 gg(Mpad / 128, HIDDEN / 128);
    for (int l = 0; l < LAYERS; ++l) {
        gemm_mfma<<<gg, 256, 0, stream>>>(hcurb, Wt + (size_t)l * HIDDEN * HIDDEN,
                                          b_gat + l * HIDDEN, nullptr, hpb,
                                          a_src + l * HIDDEN, a_dst + l * HIDDEN,
                                          sSrc, sDst, 1);
        aggregate<<<(N + 3) / 4, 256, 0, stream>>>(rowptr, emeta, wea + l * 12,
                                                   sSrc, sDst, hpb, hcur, hnext,
                                                   hnextb, N);
        float* tf = hcur; hcur = hnext; hnext = tf;
        ushort* tb = hcurb; hcurb = hnextb; hnextb = tb;
    }

    // --- output projection + LN + pool ---
    float* hp32 = hnext;
    gemm_mfma<<<gg, 256, 0, stream>>>(hcurb, Wt + (size_t)3 * HIDDEN * HIDDEN,
                                      b_out, hp32, nullptr, a_src, a_dst, sSrc, sDst, 0);
    float* gout = (float*)d_out;
    float* nemb = gout + (size_t)NUM_GRAPHS * HIDDEN;
    ln_elu<<<N, 256, 0, stream>>>(hp32, ln_out_g, ln_out_b, nemb);
    hipMemsetAsync(gout, 0, (size_t)NUM_GRAPHS * HIDDEN * 4, stream);
    pool_partial<<<(N + 127) / 128, 256, 0, stream>>>(nemb, batch, gout, N);
    pool_div<<<NUM_GRAPHS, 256, 0, stream>>>(gout, batch, N);
}